// Round 8
// baseline (132557.910 us; speedup 1.0000x reference)
//
#include <hip/hip_runtime.h>
#include <math.h>

#define N 2048
#define DIMS 784
#define BIGV 1.0e6f
#define NC 784

// two-sided block Jacobi config: 128 teams of width 16, 32x32 local tiles
#define NB 128
#define NPAIRS 64
#define NSWEEPS 18
#define NTRI 2016      // 64*63/2 upper-tri pair tiles
#define NVS  2048      // 64 pairs * 32 V row-stripes

typedef __attribute__((ext_vector_type(4))) double d4_t;

// round-robin pairing over nteams: round r in [0,nteams-1), pair m in [0,nteams/2)
__device__ __forceinline__ void rr_pairN(int r, int m, int nteams, int& bi, int& bj) {
    int n1 = nteams - 1;
    if (m == 0) { bi = n1; bj = r % n1; }
    else { bi = (r + m) % n1; bj = (r - m + n1) % n1; }
}

// pair index of team x in round r (NB teams)
__device__ __forceinline__ int rr_pidx(int r, int x) {
    const int n1 = NB - 1;
    if (x == n1) return 0;
    int m = (x - r) % n1; if (m < 0) m += n1;
    if (m == 0) return 0;
    return (m <= n1 / 2) ? m : n1 - m;
}
// partner team of x in round r
__device__ __forceinline__ int rr_partner(int r, int x) {
    const int n1 = NB - 1;
    if (x == n1) return r % n1;
    int m = (x - r) % n1; if (m < 0) m += n1;
    if (m == 0) return n1;
    if (m <= n1 / 2) return (r - m + n1) % n1;
    int m2 = n1 - m; return (r + m2) % n1;
}

// A is stored CANONICALLY: 16x16 team-sub-block (u,v) valid only at u<=v.

// ---------------- distances ----------------
__global__ void k_rowsq(const float* __restrict__ X, float* __restrict__ sq) {
    int wave = threadIdx.x >> 6, lane = threadIdx.x & 63;
    int row = blockIdx.x * 4 + wave;
    const float* xr = X + (size_t)row * DIMS;
    float s = 0.f;
    for (int k = lane; k < DIMS; k += 64) { float v = xr[k]; s += v * v; }
    for (int off = 32; off; off >>= 1) s += __shfl_down(s, off);
    if (lane == 0) sq[row] = s;
}

__global__ void __launch_bounds__(256) k_dist(const float* __restrict__ X,
                                              const float* __restrict__ sq,
                                              float* __restrict__ out) {
    __shared__ float As[64][17], Bs[64][17];
    int ti = blockIdx.y, tj = blockIdx.x, t = threadIdx.x;
    int tx = t & 15, ty = t >> 4;
    float acc[4][4] = {};
    for (int k0 = 0; k0 < DIMS; k0 += 16) {
        for (int e = 0; e < 4; e++) {
            int idx = t + e * 256; int r = idx >> 4, c = idx & 15;
            As[r][c] = X[(size_t)(ti * 64 + r) * DIMS + k0 + c];
            Bs[r][c] = X[(size_t)(tj * 64 + r) * DIMS + k0 + c];
        }
        __syncthreads();
        for (int k = 0; k < 16; k++) {
            float a[4], b[4];
            for (int e = 0; e < 4; e++) a[e] = As[ty * 4 + e][k];
            for (int f = 0; f < 4; f++) b[f] = Bs[tx * 4 + f][k];
            for (int e = 0; e < 4; e++)
                for (int f = 0; f < 4; f++) acc[e][f] += a[e] * b[f];
        }
        __syncthreads();
    }
    for (int e = 0; e < 4; e++)
        for (int f = 0; f < 4; f++) {
            int gi = ti * 64 + ty * 4 + e, gj = tj * 64 + tx * 4 + f;
            float d2 = sq[gi] + sq[gj] - 2.f * acc[e][f];
            out[(size_t)gi * N + gj] = sqrtf(fmaxf(d2, 0.f));
        }
}

// ---------------- KNN graph ----------------
__global__ void k_knn(const float* __restrict__ dist, float* __restrict__ G) {
    int i = blockIdx.x, t = threadIdx.x;
    float bv[6]; int bidx[6];
    for (int k = 0; k < 6; k++) { bv[k] = 3.4e38f; bidx[k] = N; }
    const float* dr = dist + (size_t)i * N;
    for (int j = t; j < N; j += 256) {
        float v = dr[j];
        bool ins = (v < bv[5]) || (v == bv[5] && j < bidx[5]);
        if (ins) {
            int k = 5;
            while (k > 0) {
                bool mv = (v < bv[k - 1]) || (v == bv[k - 1] && j < bidx[k - 1]);
                if (!mv) break;
                bv[k] = bv[k - 1]; bidx[k] = bidx[k - 1]; k--;
            }
            bv[k] = v; bidx[k] = j;
        }
    }
    __shared__ float lv[256][6]; __shared__ int li[256][6];
    for (int k = 0; k < 6; k++) { lv[t][k] = bv[k]; li[t][k] = bidx[k]; }
    __syncthreads();
    for (int off = 128; off >= 1; off >>= 1) {
        if (t < off) {
            float av[6], cv[6]; int ai[6], ci[6];
            for (int k = 0; k < 6; k++) { av[k] = lv[t][k]; ai[k] = li[t][k]; cv[k] = lv[t + off][k]; ci[k] = li[t + off][k]; }
            float mv[6]; int mi[6]; int pa = 0, pb = 0;
            for (int k = 0; k < 6; k++) {
                bool ta;
                if (pa >= 6) ta = false;
                else if (pb >= 6) ta = true;
                else ta = (av[pa] < cv[pb]) || (av[pa] == cv[pb] && ai[pa] < ci[pb]);
                if (ta) { mv[k] = av[pa]; mi[k] = ai[pa]; pa++; }
                else    { mv[k] = cv[pb]; mi[k] = ci[pb]; pb++; }
            }
            for (int k = 0; k < 6; k++) { lv[t][k] = mv[k]; li[t][k] = mi[k]; }
        }
        __syncthreads();
    }
    float sv[6]; int si[6];
    for (int k = 0; k < 6; k++) { sv[k] = lv[0][k]; si[k] = li[0][k]; }
    for (int j = t; j < N; j += 256) {
        float val = BIGV;
        for (int k = 0; k < 6; k++) if (j == si[k]) val = sv[k];
        G[(size_t)i * N + j] = val;
    }
}

__global__ void k_symdiag(float* __restrict__ G) {
    int idx = blockIdx.x * 256 + threadIdx.x;
    int i = idx >> 11, j = idx & 2047;
    if (i == j) { G[idx] = 0.f; return; }
    if (j > i) {
        float a = G[(size_t)i * N + j], b = G[(size_t)j * N + i];
        float m = fminf(a, b);
        G[(size_t)i * N + j] = m; G[(size_t)j * N + i] = m;
    }
}

// ---------------- blocked Floyd-Warshall ----------------
__global__ void __launch_bounds__(256) k_fw12(float* __restrict__ D, int kb) {
    __shared__ float KK[64][65], C[64][65];
    int bx = blockIdx.x, t = threadIdx.x;
    for (int e = 0; e < 16; e++) { int idx = t + e * 256; int r = idx >> 6, c = idx & 63;
        KK[r][c] = D[(size_t)(kb * 64 + r) * N + kb * 64 + c]; }
    __syncthreads();
    int r0 = t >> 2, c0 = (t & 3) * 16;
    for (int k = 0; k < 64; k++) {
        float dk = KK[r0][k];
        for (int c = 0; c < 16; c++) KK[r0][c0 + c] = fminf(KK[r0][c0 + c], dk + KK[k][c0 + c]);
        __syncthreads();
    }
    if (bx == 62) {
        for (int e = 0; e < 16; e++) { int idx = t + e * 256; int r = idx >> 6, c = idx & 63;
            D[(size_t)(kb * 64 + r) * N + kb * 64 + c] = KK[r][c]; }
        return;
    }
    bool rowstripe = bx < 31;
    int o = rowstripe ? bx : bx - 31;
    o += (o >= kb) ? 1 : 0;
    int baseR = rowstripe ? kb : o;
    int baseC = rowstripe ? o : kb;
    for (int e = 0; e < 16; e++) { int idx = t + e * 256; int r = idx >> 6, c = idx & 63;
        C[r][c] = D[(size_t)(baseR * 64 + r) * N + baseC * 64 + c]; }
    __syncthreads();
    if (rowstripe) {
        for (int k = 0; k < 64; k++) {
            float dk = KK[r0][k];
            for (int c = 0; c < 16; c++) C[r0][c0 + c] = fminf(C[r0][c0 + c], dk + C[k][c0 + c]);
            __syncthreads();
        }
    } else {
        for (int k = 0; k < 64; k++) {
            float dk = C[r0][k];
            for (int c = 0; c < 16; c++) C[r0][c0 + c] = fminf(C[r0][c0 + c], dk + KK[k][c0 + c]);
            __syncthreads();
        }
    }
    for (int e = 0; e < 16; e++) { int idx = t + e * 256; int r = idx >> 6, c = idx & 63;
        D[(size_t)(baseR * 64 + r) * N + baseC * 64 + c] = C[r][c]; }
}

__global__ void __launch_bounds__(256) k_fw3(float* __restrict__ D, int kb) {
    int bi = blockIdx.y, bj = blockIdx.x;
    if (bi == kb || bj == kb) return;
    __shared__ float R[64][65], Cl[64][65];
    int t = threadIdx.x;
    for (int e = 0; e < 16; e++) { int idx = t + e * 256; int r = idx >> 6, c = idx & 63;
        R[r][c]  = D[(size_t)(bi * 64 + r) * N + kb * 64 + c];
        Cl[r][c] = D[(size_t)(kb * 64 + r) * N + bj * 64 + c]; }
    __syncthreads();
    int r0 = (t >> 4) * 4, c0 = (t & 15) * 4;
    float acc[4][4];
    for (int e = 0; e < 4; e++) for (int f = 0; f < 4; f++) acc[e][f] = 3.4e38f;
    for (int k = 0; k < 64; k++) {
        float a[4], b[4];
        for (int e = 0; e < 4; e++) a[e] = R[r0 + e][k];
        for (int f = 0; f < 4; f++) b[f] = Cl[k][c0 + f];
        for (int e = 0; e < 4; e++)
            for (int f = 0; f < 4; f++) acc[e][f] = fminf(acc[e][f], a[e] + b[f]);
    }
    for (int e = 0; e < 4; e++)
        for (int f = 0; f < 4; f++) {
            size_t off = (size_t)(bi * 64 + r0 + e) * N + bj * 64 + c0 + f;
            D[off] = fminf(D[off], acc[e][f]);
        }
}

// ---------------- double centering ----------------
__global__ void k_rowmean(const float* __restrict__ D, double* __restrict__ rm) {
    int i = blockIdx.x, t = threadIdx.x;
    const float* dr = D + (size_t)i * N;
    double s = 0;
    for (int j = t; j < N; j += 256) { double d = (double)dr[j]; s += d * d; }
    __shared__ double red[256];
    red[t] = s; __syncthreads();
    for (int off = 128; off; off >>= 1) { if (t < off) red[t] += red[t + off]; __syncthreads(); }
    if (t == 0) rm[i] = red[0] / (double)N;
}

__global__ void k_grand(const double* __restrict__ rm, double* __restrict__ gm) {
    int t = threadIdx.x;
    double s = 0;
    for (int i = t; i < N; i += 256) s += rm[i];
    __shared__ double red[256];
    red[t] = s; __syncthreads();
    for (int off = 128; off; off >>= 1) { if (t < off) red[t] += red[t + off]; __syncthreads(); }
    if (t == 0) gm[0] = red[0] / (double)N;
}

__global__ void k_buildB(const float* __restrict__ D, const double* __restrict__ rm,
                         const double* __restrict__ gm, double* __restrict__ A) {
    int idx = blockIdx.x * 256 + threadIdx.x;
    int i = idx >> 11, j = idx & 2047;
    double d = (double)D[idx];
    A[idx] = -0.5 * (d * d - rm[i] - rm[j] + gm[0]);
}

__global__ void k_setV(float* __restrict__ V) {
    int idx = blockIdx.x * 256 + threadIdx.x;
    int i = idx >> 11, j = idx & 2047;
    V[idx] = (i == j) ? 1.f : 0.f;
}

// ---------------- Jacobi control ----------------
__global__ void k_initflags(unsigned* flags) { flags[0] = 0u; flags[1] = 0u; flags[2] = 0u; }
__global__ void k_sweepctl(unsigned* flags) {
    if (!flags[2]) {
        float mo = __uint_as_float(flags[0]), md = __uint_as_float(flags[1]);
        if (md > 0.f && mo <= 2e-9f * md) { flags[2] = 1u; return; }
        flags[0] = 0u; flags[1] = 0u;
    }
}

// ---------------- task bodies (shared-union via smem base pointer) ----------------
// smem: double[2432] = 19456 B per block.

// V <- V*Q for one 64-row stripe
__device__ __forceinline__ void vapply_task(float* __restrict__ V, const double* __restrict__ qbP,
                                            const int* __restrict__ qp, int rnd, int task, int t,
                                            double* smem) {
    int p = task >> 5, rt = task & 31;
    if (!qp[p]) return;
    float (*Qs)[33] = (float(*)[33])smem;
    float (*Tv)[33] = (float(*)[33])(smem + 528);
    int bi, bj; rr_pairN(rnd, p, NB, bi, bj);
    for (int e = 0; e < 4; e++) {
        int idx = t + e * 256; int a = idx >> 5, c = idx & 31;
        Qs[a][c] = (float)qbP[(size_t)p * 1024 + idx];
    }
    for (int e = 0; e < 8; e++) {
        int idx = t + e * 256; int a = idx >> 5, c = idx & 31;
        int gc = (c < 16) ? bi * 16 + c : bj * 16 + (c - 16);
        Tv[a][c] = V[(size_t)(rt * 64 + a) * N + gc];
    }
    __syncthreads();
    int r0 = (t >> 4) * 4, c0 = (t & 15) * 2;
    float acc[4][2] = {};
    for (int y = 0; y < 32; y++) {
        float q0 = Qs[y][c0], q1 = Qs[y][c0 + 1];
        for (int e = 0; e < 4; e++) {
            float vv = Tv[r0 + e][y];
            acc[e][0] += vv * q0; acc[e][1] += vv * q1;
        }
    }
    for (int e = 0; e < 4; e++)
        for (int f = 0; f < 2; f++) {
            int x = c0 + f;
            int gc = (x < 16) ? bi * 16 + x : bj * 16 + (x - 16);
            V[(size_t)(rt * 64 + r0 + e) * N + gc] = acc[e][f];
        }
}

// local 32x32 Jacobi on pair p of `round`.
// Inner sweep runs WAVE-SYNCHRONOUS on wave 0 (zero s_barriers in the 31 micro-rounds):
// same-wave DS ops execute in order at the LDS; __builtin_amdgcn_wave_barrier()
// fences compiler reordering. Waves 1-3 wait at the final __syncthreads.
__device__ __forceinline__ void local_task(double* __restrict__ A, double* __restrict__ qb,
                                           int* __restrict__ qfl, unsigned* __restrict__ flags,
                                           int round, int par, int p, int t, double* smem) {
    double* qbC = qb + (size_t)par * (NPAIRS * 1024);
    int* qflC = qfl + par * NPAIRS;
    if (flags[2]) { if (t == 0) qflC[p] = 0; return; }
    double (*M)[33] = (double(*)[33])smem;
    double (*Q)[33] = (double(*)[33])(smem + 1056);
    double* cA = smem + 2112; double* sA = smem + 2128;
    int* ppA = (int*)(smem + 2144); int* qqA = ppA + 16;
    float* rbuf = (float*)(smem + 2160);       // 8 floats: per-wave off/diag maxima
    int* everr = (int*)(smem + 2416);
    int bi, bj; rr_pairN(round, p, NB, bi, bj);

    int rr = t >> 4, cc = t & 15;
    int tm[2] = { bi, bj };
    float offm = 0.f, diagm = 0.f;
    for (int s = 0; s < 4; s++) {
        int u = tm[s >> 1], v = tm[s & 1];
        double val; int dr, dc;
        if (u <= v) { val = A[(size_t)(u * 16 + rr) * N + v * 16 + cc]; dr = (s >> 1) * 16 + rr; dc = (s & 1) * 16 + cc; }
        else        { val = A[(size_t)(v * 16 + rr) * N + u * 16 + cc]; dr = (s >> 1) * 16 + cc; dc = (s & 1) * 16 + rr; }
        M[dr][dc] = val;
        float av = (float)fabs(val);
        if (s == 0 || s == 3) { if (rr == cc) diagm = fmaxf(diagm, av); else offm = fmaxf(offm, av); }
        else offm = fmaxf(offm, av);
    }
    for (int e = 0; e < 4; e++) {
        int idx = t + e * 256; int x = idx >> 5, y = idx & 31;
        Q[x][y] = (x == y) ? 1.0 : 0.0;
    }
    // per-wave shuffle max, then one barrier
    for (int off = 32; off; off >>= 1) {
        offm = fmaxf(offm, __shfl_down(offm, off));
        diagm = fmaxf(diagm, __shfl_down(diagm, off));
    }
    if ((t & 63) == 0) { rbuf[t >> 6] = offm; rbuf[4 + (t >> 6)] = diagm; }
    if (t == 0) *everr = 0;
    __syncthreads();
    float off0 = fmaxf(fmaxf(rbuf[0], rbuf[1]), fmaxf(rbuf[2], rbuf[3]));
    float dmaxf = fmaxf(fmaxf(rbuf[4], rbuf[5]), fmaxf(rbuf[6], rbuf[7]));
    if (t == 0) { atomicMax(flags + 0, __float_as_uint(off0)); atomicMax(flags + 1, __float_as_uint(dmaxf)); }
    double dmax = (double)dmaxf;
    if ((double)off0 <= 1e-9 * dmax) { if (t == 0) qflC[p] = 0; return; }
    double thr = fmax(1e-13 * dmax, 1e-5 * (double)off0);

    if (t < 64) {   // wave 0 only: barrier-free inner sweep
        for (int ir = 0; ir < 31; ir++) {
            if (t < 16) {
                int pp, qq; rr_pairN(ir, t, 32, pp, qq);
                double app = M[pp][pp], aqq = M[qq][qq], apq = M[pp][qq];
                double c = 1.0, sn = 0.0;
                if (fabs(apq) > thr) {
                    double tau = (aqq - app) / (2.0 * apq);
                    double tt2 = ((tau >= 0.0) ? 1.0 : -1.0) / (fabs(tau) + sqrt(1.0 + tau * tau));
                    c = 1.0 / sqrt(1.0 + tt2 * tt2);
                    sn = tt2 * c;
                    *everr = 1;
                }
                ppA[t] = pp; qqA[t] = qq; cA[t] = c; sA[t] = sn;
            }
            __builtin_amdgcn_wave_barrier();
            // col updates: M <- M*J, Q <- Q*J  (512 slots, 8/lane)
            for (int e = 0; e < 8; e++) {
                int slot = t + e * 64; int mm = slot >> 5, k = slot & 31;
                double sn = sA[mm];
                if (sn != 0.0) {
                    int pp = ppA[mm], qq = qqA[mm]; double c = cA[mm];
                    double a = M[k][pp], b = M[k][qq];
                    M[k][pp] = c * a - sn * b; M[k][qq] = sn * a + c * b;
                    a = Q[k][pp]; b = Q[k][qq];
                    Q[k][pp] = c * a - sn * b; Q[k][qq] = sn * a + c * b;
                }
            }
            __builtin_amdgcn_wave_barrier();
            // row updates: M <- J^T * M (512 slots, 8/lane)
            for (int e = 0; e < 8; e++) {
                int slot = t + e * 64; int mm = slot >> 5, k = slot & 31;
                double sn = sA[mm];
                if (sn != 0.0) {
                    int pp = ppA[mm], qq = qqA[mm]; double c = cA[mm];
                    double a = M[pp][k], b = M[qq][k];
                    M[pp][k] = c * a - sn * b; M[qq][k] = sn * a + c * b;
                }
            }
            __builtin_amdgcn_wave_barrier();
        }
    }
    __syncthreads();
    int ev = *everr;
    if (t == 0) qflC[p] = ev;
    if (ev) {
        for (int e = 0; e < 4; e++) {
            int idx = t + e * 256; int x = idx >> 5, y = idx & 31;
            qbC[(size_t)p * 1024 + idx] = Q[x][y];
        }
        A[(size_t)(bi * 16 + rr) * N + bi * 16 + cc] = M[rr][cc];
        A[(size_t)(bj * 16 + rr) * N + bj * 16 + cc] = M[16 + rr][16 + cc];
        if (bi <= bj) A[(size_t)(bi * 16 + rr) * N + bj * 16 + cc] = M[rr][16 + cc];
        else          A[(size_t)(bj * 16 + rr) * N + bi * 16 + cc] = M[16 + rr][cc];
    }
}

// tri-apply: A <- Qr^T A Qc on pair tile (pr,pc), fp64 MFMA, canonical storage
__device__ __forceinline__ void tri_task(double* __restrict__ A, const double* __restrict__ qbC,
                                         const int* __restrict__ qflC, int round, int pr, int pc,
                                         int t, double* smem) {
    int fr = qflC[pr], fc = qflC[pc];
    if (!fr && !fc) return;
    double (*T)[33] = (double(*)[33])smem;
    double (*Qb)[33] = (double(*)[33])(smem + 1056);
    int bir, bjr, bic, bjc;
    rr_pairN(round, pr, NB, bir, bjr);
    rr_pairN(round, pc, NB, bic, bjc);
    int rt[2] = { bir, bjr }, ct[2] = { bic, bjc };
    int rr = t >> 4, cc = t & 15;
    if (fr) {
        for (int e = 0; e < 4; e++) {
            int idx = t + e * 256; int a = idx >> 5, b = idx & 31;
            Qb[a][b] = qbC[(size_t)pr * 1024 + idx];
        }
    }
    for (int s = 0; s < 4; s++) {
        int u = rt[s >> 1], v = ct[s & 1];
        if (u <= v) T[(s >> 1) * 16 + rr][(s & 1) * 16 + cc] = A[(size_t)(u * 16 + rr) * N + v * 16 + cc];
        else        T[(s >> 1) * 16 + cc][(s & 1) * 16 + rr] = A[(size_t)(v * 16 + rr) * N + u * 16 + cc];
    }
    __syncthreads();
    int wv = t >> 6, ln = t & 63;
    int i0 = (wv >> 1) * 16, j0 = (wv & 1) * 16;
    int li = ln & 15, lk = ln >> 4;
    if (fr) {
        d4_t d = {0.0, 0.0, 0.0, 0.0};
        #pragma unroll
        for (int y0 = 0; y0 < 32; y0 += 4) {
            double a = Qb[y0 + lk][i0 + li];
            double b = T[y0 + lk][j0 + li];
            d = __builtin_amdgcn_mfma_f64_16x16x4f64(a, b, d, 0, 0, 0);
        }
        __syncthreads();
        #pragma unroll
        for (int v = 0; v < 4; v++) T[i0 + lk * 4 + v][j0 + li] = d[v];
        __syncthreads();
    }
    if (fc) {
        for (int e = 0; e < 4; e++) {
            int idx = t + e * 256; int a = idx >> 5, b = idx & 31;
            Qb[a][b] = qbC[(size_t)pc * 1024 + idx];
        }
        __syncthreads();
        d4_t d = {0.0, 0.0, 0.0, 0.0};
        #pragma unroll
        for (int y0 = 0; y0 < 32; y0 += 4) {
            double a = T[i0 + li][y0 + lk];
            double b = Qb[y0 + lk][j0 + li];
            d = __builtin_amdgcn_mfma_f64_16x16x4f64(a, b, d, 0, 0, 0);
        }
        __syncthreads();
        #pragma unroll
        for (int v = 0; v < 4; v++) T[i0 + lk * 4 + v][j0 + li] = d[v];
        __syncthreads();
    }
    for (int s = 0; s < 4; s++) {
        int u = rt[s >> 1], v = ct[s & 1];
        if (u <= v) A[(size_t)(u * 16 + rr) * N + v * 16 + cc] = T[(s >> 1) * 16 + rr][(s & 1) * 16 + cc];
        else        A[(size_t)(v * 16 + rr) * N + u * 16 + cc] = T[(s >> 1) * 16 + cc][(s & 1) * 16 + rr];
    }
}

// ---------------- pipelined Jacobi kernels ----------------
// round 0 local, standalone prologue
__global__ void __launch_bounds__(256) k_local0(double* __restrict__ A, double* __restrict__ qb,
                                                int* __restrict__ qfl, unsigned* __restrict__ flags) {
    __shared__ double smem[2432];
    local_task(A, qb, qfl, flags, 0, 0, (int)blockIdx.x, (int)threadIdx.x, smem);
}

// fused single launch per round:
//   blocks 0..63: [inlined critical tri(round) for this next-pair] then local(nextRound)
//   blocks 64..64+NTRI-1: tri_rest(round) (critical tasks excluded)
//   remaining: V-apply(round)
__global__ void __launch_bounds__(256) k_fused(double* __restrict__ A, float* __restrict__ V,
                                               double* __restrict__ qb, int* __restrict__ qfl,
                                               unsigned* __restrict__ flags,
                                               int round, int par, int nextRound, int nextPar,
                                               int nextValid) {
    __shared__ double smem[2432];
    int t = threadIdx.x, blk = blockIdx.x;
    if (blk < NPAIRS) {
        if (!flags[2]) {
            int u, v; rr_pairN(nextRound, blk, NB, u, v);
            int a = rr_pidx(round, u), b = rr_pidx(round, v);
            int pr = min(a, b), pc = max(a, b);
            tri_task(A, qb + (size_t)par * (NPAIRS * 1024), qfl + par * NPAIRS,
                     round, pr, pc, t, smem);
            __syncthreads();
        }
        if (nextValid) local_task(A, qb, qfl, flags, nextRound, nextPar, blk, t, smem);
    } else if (blk < NPAIRS + NTRI) {
        if (flags[2]) return;
        int task = blk - NPAIRS;
        int pr = 0, rem = task;
        while (rem >= 63 - pr) { rem -= 63 - pr; pr++; }
        int pc = pr + 1 + rem;
        int bir, bjr, bic, bjc;
        rr_pairN(round, pr, NB, bir, bjr);
        rr_pairN(round, pc, NB, bic, bjc);
        #pragma unroll
        for (int s = 0; s < 4; s++) {
            int tu = (s >> 1) ? bjr : bir, tv = (s & 1) ? bjc : bic;
            if (rr_partner(nextRound, tu) == tv) return;   // critical: handled in local blocks
        }
        tri_task(A, qb + (size_t)par * (NPAIRS * 1024), qfl + par * NPAIRS, round, pr, pc, t, smem);
    } else {
        if (flags[2]) return;
        vapply_task(V, qb + (size_t)par * (NPAIRS * 1024), qfl + par * NPAIRS,
                    round, blk - NPAIRS - NTRI, t, smem);
    }
}

// ---------------- epilogue ----------------
__global__ void k_lambda(const double* __restrict__ A, double* __restrict__ lam) {
    int i = blockIdx.x * 256 + threadIdx.x;
    if (i < N) lam[i] = A[(size_t)i * N + i];
}

__global__ void __launch_bounds__(1024) k_sort(const double* __restrict__ lam,
                                               double* __restrict__ lams, int* __restrict__ order) {
    __shared__ double v[2048]; __shared__ int ix[2048];
    int t = threadIdx.x;
    v[t] = lam[t]; v[t + 1024] = lam[t + 1024];
    ix[t] = t; ix[t + 1024] = t + 1024;
    __syncthreads();
    for (int k = 2; k <= 2048; k <<= 1) {
        for (int j = k >> 1; j > 0; j >>= 1) {
            int l = ((t & ~(j - 1)) << 1) | (t & (j - 1));
            int partner = l | j;
            double va = v[l], vb = v[partner]; int ia = ix[l], ib = ix[partner];
            bool before = (va > vb) || (va == vb && ia < ib);
            bool asc = ((l & k) == 0);
            bool doSwap = asc ? (!before) : before;
            if (doSwap) { v[l] = vb; v[partner] = va; ix[l] = ib; ix[partner] = ia; }
            __syncthreads();
        }
    }
    lams[t] = v[t]; lams[t + 1024] = v[t + 1024];
    order[t] = ix[t]; order[t + 1024] = ix[t + 1024];
}

__global__ void k_out(const float* __restrict__ Vm, const double* __restrict__ lams,
                      const int* __restrict__ order, float* __restrict__ out) {
    int c = blockIdx.x, t = threadIdx.x;
    int col = order[c];
    __shared__ float rv[256]; __shared__ int ri[256];
    float bv = -1.f; int bidx = N;
    for (int i = t; i < N; i += 256) {
        float av = fabsf(Vm[(size_t)i * N + col]);
        if (av > bv || (av == bv && i < bidx)) { bv = av; bidx = i; }
    }
    rv[t] = bv; ri[t] = bidx;
    __syncthreads();
    for (int off = 128; off; off >>= 1) {
        if (t < off) {
            if (rv[t + off] > rv[t] || (rv[t + off] == rv[t] && ri[t + off] < ri[t])) {
                rv[t] = rv[t + off]; ri[t] = ri[t + off];
            }
        }
        __syncthreads();
    }
    float sv = Vm[(size_t)ri[0] * N + col];
    float s = (sv > 0.f) ? 1.f : ((sv < 0.f) ? -1.f : 0.f);
    double lv = lams[c];
    float f = s * (float)sqrt(lv > 0.0 ? lv : 0.0);
    for (int i = t; i < N; i += 256) out[(size_t)i * NC + c] = Vm[(size_t)i * N + col] * f;
}

extern "C" void kernel_launch(void* const* d_in, const int* in_sizes, int n_in,
                              void* d_out, int out_size, void* d_ws, size_t ws_size,
                              hipStream_t stream) {
    (void)in_sizes; (void)n_in; (void)out_size; (void)ws_size;
    const float* X = (const float*)d_in[0];
    float* out = (float*)d_out;

    double* rm  = (double*)d_ws;                 // N
    double* gm  = rm + N;                        // 1 (+7 pad)
    double* lam = gm + 8;                        // N
    double* lams= lam + N;                       // N
    double* A   = lams + N;                      // N*N fp64
    double* qb  = A + (size_t)N * N;             // 2 * NPAIRS*1024 fp64 (double-buffered)
    float* Dg   = (float*)(qb + 2 * (size_t)NPAIRS * 1024); // N*N f32
    float* Vm   = Dg + (size_t)N * N;            // N*N f32
    float* sq   = Vm + (size_t)N * N;            // N
    int* order  = (int*)(sq + N);                // N
    int* qfl    = order + N;                     // 2 * NPAIRS
    unsigned* flags = (unsigned*)(qfl + 2 * NPAIRS); // 3
    float* dist = (float*)A;                     // alias: dist dies before A is born

    // 1. pairwise distances
    k_rowsq<<<N / 4, 256, 0, stream>>>(X, sq);
    k_dist<<<dim3(32, 32), 256, 0, stream>>>(X, sq, dist);

    // 2. KNN graph
    k_knn<<<N, 256, 0, stream>>>(dist, Dg);
    k_symdiag<<<(N * N) / 256, 256, 0, stream>>>(Dg);

    // 3. blocked Floyd-Warshall
    for (int kb = 0; kb < N / 64; kb++) {
        k_fw12<<<63, 256, 0, stream>>>(Dg, kb);
        k_fw3<<<dim3(32, 32), 256, 0, stream>>>(Dg, kb);
    }

    // 4. double centering -> B (fp64)
    k_rowmean<<<N, 256, 0, stream>>>(Dg, rm);
    k_grand<<<1, 256, 0, stream>>>(rm, gm);
    k_buildB<<<(N * N) / 256, 256, 0, stream>>>(Dg, rm, gm, A);
    k_setV<<<(N * N) / 256, 256, 0, stream>>>(Vm);
    k_initflags<<<1, 1, 0, stream>>>(flags);

    // 5. pipelined two-sided block Jacobi, ONE launch per round:
    //    local(0) prologue; per round g: fused{ critTri(g)+local(g+1) || tri_rest(g) || V(g) }.
    const int G = NSWEEPS * (NB - 1);
    k_local0<<<NPAIRS, 256, 0, stream>>>(A, qb, qfl, flags);
    for (int g = 0; g < G; g++) {
        int round = g % (NB - 1), par = g & 1;
        int nr = (g + 1) % (NB - 1), npar = (g + 1) & 1;
        int nv = (g + 1 < G) ? 1 : 0;
        if (((g + 1) % (NB - 1)) == 0)
            k_sweepctl<<<1, 1, 0, stream>>>(flags);
        k_fused<<<NPAIRS + NTRI + NVS, 256, 0, stream>>>(A, Vm, qb, qfl, flags,
                                                         round, par, nr, npar, nv);
    }

    // 6. sort eigenvalues, sign-fix, scale, write output
    k_lambda<<<N / 256, 256, 0, stream>>>(A, lam);
    k_sort<<<1, 1024, 0, stream>>>(lam, lams, order);
    k_out<<<NC, 256, 0, stream>>>(Vm, lams, order, out);
}

// Round 9
// 65038.806 us; speedup vs baseline: 2.0381x; 2.0381x over previous
//
#include <hip/hip_runtime.h>
#include <math.h>

#define N 2048
#define DIMS 784
#define BIGV 1.0e6f
#define NC 784

// two-sided block Jacobi config: 128 teams of width 16, 32x32 local tiles
#define NB 128
#define NPAIRS 64
#define NSWEEPS 18
#define NTRI 2016      // 64*63/2 upper-tri pair tiles
#define NVS  2048      // 64 pairs * 32 V row-stripes

typedef __attribute__((ext_vector_type(4))) double d4_t;

// round-robin pairing over nteams: round r in [0,nteams-1), pair m in [0,nteams/2)
__device__ __forceinline__ void rr_pairN(int r, int m, int nteams, int& bi, int& bj) {
    int n1 = nteams - 1;
    if (m == 0) { bi = n1; bj = r % n1; }
    else { bi = (r + m) % n1; bj = (r - m + n1) % n1; }
}

// pair index of team x in round r (NB teams)
__device__ __forceinline__ int rr_pidx(int r, int x) {
    const int n1 = NB - 1;
    if (x == n1) return 0;
    int m = (x - r) % n1; if (m < 0) m += n1;
    if (m == 0) return 0;
    return (m <= n1 / 2) ? m : n1 - m;
}
// partner team of x in round r
__device__ __forceinline__ int rr_partner(int r, int x) {
    const int n1 = NB - 1;
    if (x == n1) return r % n1;
    int m = (x - r) % n1; if (m < 0) m += n1;
    if (m == 0) return n1;
    if (m <= n1 / 2) return (r - m + n1) % n1;
    int m2 = n1 - m; return (r + m2) % n1;
}

// A is stored CANONICALLY: 16x16 team-sub-block (u,v) valid only at u<=v.

// ---------------- distances ----------------
__global__ void k_rowsq(const float* __restrict__ X, float* __restrict__ sq) {
    int wave = threadIdx.x >> 6, lane = threadIdx.x & 63;
    int row = blockIdx.x * 4 + wave;
    const float* xr = X + (size_t)row * DIMS;
    float s = 0.f;
    for (int k = lane; k < DIMS; k += 64) { float v = xr[k]; s += v * v; }
    for (int off = 32; off; off >>= 1) s += __shfl_down(s, off);
    if (lane == 0) sq[row] = s;
}

__global__ void __launch_bounds__(256) k_dist(const float* __restrict__ X,
                                              const float* __restrict__ sq,
                                              float* __restrict__ out) {
    __shared__ float As[64][17], Bs[64][17];
    int ti = blockIdx.y, tj = blockIdx.x, t = threadIdx.x;
    int tx = t & 15, ty = t >> 4;
    float acc[4][4] = {};
    for (int k0 = 0; k0 < DIMS; k0 += 16) {
        for (int e = 0; e < 4; e++) {
            int idx = t + e * 256; int r = idx >> 4, c = idx & 15;
            As[r][c] = X[(size_t)(ti * 64 + r) * DIMS + k0 + c];
            Bs[r][c] = X[(size_t)(tj * 64 + r) * DIMS + k0 + c];
        }
        __syncthreads();
        for (int k = 0; k < 16; k++) {
            float a[4], b[4];
            for (int e = 0; e < 4; e++) a[e] = As[ty * 4 + e][k];
            for (int f = 0; f < 4; f++) b[f] = Bs[tx * 4 + f][k];
            for (int e = 0; e < 4; e++)
                for (int f = 0; f < 4; f++) acc[e][f] += a[e] * b[f];
        }
        __syncthreads();
    }
    for (int e = 0; e < 4; e++)
        for (int f = 0; f < 4; f++) {
            int gi = ti * 64 + ty * 4 + e, gj = tj * 64 + tx * 4 + f;
            float d2 = sq[gi] + sq[gj] - 2.f * acc[e][f];
            out[(size_t)gi * N + gj] = sqrtf(fmaxf(d2, 0.f));
        }
}

// ---------------- KNN graph ----------------
__global__ void k_knn(const float* __restrict__ dist, float* __restrict__ G) {
    int i = blockIdx.x, t = threadIdx.x;
    float bv[6]; int bidx[6];
    for (int k = 0; k < 6; k++) { bv[k] = 3.4e38f; bidx[k] = N; }
    const float* dr = dist + (size_t)i * N;
    for (int j = t; j < N; j += 256) {
        float v = dr[j];
        bool ins = (v < bv[5]) || (v == bv[5] && j < bidx[5]);
        if (ins) {
            int k = 5;
            while (k > 0) {
                bool mv = (v < bv[k - 1]) || (v == bv[k - 1] && j < bidx[k - 1]);
                if (!mv) break;
                bv[k] = bv[k - 1]; bidx[k] = bidx[k - 1]; k--;
            }
            bv[k] = v; bidx[k] = j;
        }
    }
    __shared__ float lv[256][6]; __shared__ int li[256][6];
    for (int k = 0; k < 6; k++) { lv[t][k] = bv[k]; li[t][k] = bidx[k]; }
    __syncthreads();
    for (int off = 128; off >= 1; off >>= 1) {
        if (t < off) {
            float av[6], cv[6]; int ai[6], ci[6];
            for (int k = 0; k < 6; k++) { av[k] = lv[t][k]; ai[k] = li[t][k]; cv[k] = lv[t + off][k]; ci[k] = li[t + off][k]; }
            float mv[6]; int mi[6]; int pa = 0, pb = 0;
            for (int k = 0; k < 6; k++) {
                bool ta;
                if (pa >= 6) ta = false;
                else if (pb >= 6) ta = true;
                else ta = (av[pa] < cv[pb]) || (av[pa] == cv[pb] && ai[pa] < ci[pb]);
                if (ta) { mv[k] = av[pa]; mi[k] = ai[pa]; pa++; }
                else    { mv[k] = cv[pb]; mi[k] = ci[pb]; pb++; }
            }
            for (int k = 0; k < 6; k++) { lv[t][k] = mv[k]; li[t][k] = mi[k]; }
        }
        __syncthreads();
    }
    float sv[6]; int si[6];
    for (int k = 0; k < 6; k++) { sv[k] = lv[0][k]; si[k] = li[0][k]; }
    for (int j = t; j < N; j += 256) {
        float val = BIGV;
        for (int k = 0; k < 6; k++) if (j == si[k]) val = sv[k];
        G[(size_t)i * N + j] = val;
    }
}

__global__ void k_symdiag(float* __restrict__ G) {
    int idx = blockIdx.x * 256 + threadIdx.x;
    int i = idx >> 11, j = idx & 2047;
    if (i == j) { G[idx] = 0.f; return; }
    if (j > i) {
        float a = G[(size_t)i * N + j], b = G[(size_t)j * N + i];
        float m = fminf(a, b);
        G[(size_t)i * N + j] = m; G[(size_t)j * N + i] = m;
    }
}

// ---------------- blocked Floyd-Warshall ----------------
__global__ void __launch_bounds__(256) k_fw12(float* __restrict__ D, int kb) {
    __shared__ float KK[64][65], C[64][65];
    int bx = blockIdx.x, t = threadIdx.x;
    for (int e = 0; e < 16; e++) { int idx = t + e * 256; int r = idx >> 6, c = idx & 63;
        KK[r][c] = D[(size_t)(kb * 64 + r) * N + kb * 64 + c]; }
    __syncthreads();
    int r0 = t >> 2, c0 = (t & 3) * 16;
    for (int k = 0; k < 64; k++) {
        float dk = KK[r0][k];
        for (int c = 0; c < 16; c++) KK[r0][c0 + c] = fminf(KK[r0][c0 + c], dk + KK[k][c0 + c]);
        __syncthreads();
    }
    if (bx == 62) {
        for (int e = 0; e < 16; e++) { int idx = t + e * 256; int r = idx >> 6, c = idx & 63;
            D[(size_t)(kb * 64 + r) * N + kb * 64 + c] = KK[r][c]; }
        return;
    }
    bool rowstripe = bx < 31;
    int o = rowstripe ? bx : bx - 31;
    o += (o >= kb) ? 1 : 0;
    int baseR = rowstripe ? kb : o;
    int baseC = rowstripe ? o : kb;
    for (int e = 0; e < 16; e++) { int idx = t + e * 256; int r = idx >> 6, c = idx & 63;
        C[r][c] = D[(size_t)(baseR * 64 + r) * N + baseC * 64 + c]; }
    __syncthreads();
    if (rowstripe) {
        for (int k = 0; k < 64; k++) {
            float dk = KK[r0][k];
            for (int c = 0; c < 16; c++) C[r0][c0 + c] = fminf(C[r0][c0 + c], dk + C[k][c0 + c]);
            __syncthreads();
        }
    } else {
        for (int k = 0; k < 64; k++) {
            float dk = C[r0][k];
            for (int c = 0; c < 16; c++) C[r0][c0 + c] = fminf(C[r0][c0 + c], dk + KK[k][c0 + c]);
            __syncthreads();
        }
    }
    for (int e = 0; e < 16; e++) { int idx = t + e * 256; int r = idx >> 6, c = idx & 63;
        D[(size_t)(baseR * 64 + r) * N + baseC * 64 + c] = C[r][c]; }
}

__global__ void __launch_bounds__(256) k_fw3(float* __restrict__ D, int kb) {
    int bi = blockIdx.y, bj = blockIdx.x;
    if (bi == kb || bj == kb) return;
    __shared__ float R[64][65], Cl[64][65];
    int t = threadIdx.x;
    for (int e = 0; e < 16; e++) { int idx = t + e * 256; int r = idx >> 6, c = idx & 63;
        R[r][c]  = D[(size_t)(bi * 64 + r) * N + kb * 64 + c];
        Cl[r][c] = D[(size_t)(kb * 64 + r) * N + bj * 64 + c]; }
    __syncthreads();
    int r0 = (t >> 4) * 4, c0 = (t & 15) * 4;
    float acc[4][4];
    for (int e = 0; e < 4; e++) for (int f = 0; f < 4; f++) acc[e][f] = 3.4e38f;
    for (int k = 0; k < 64; k++) {
        float a[4], b[4];
        for (int e = 0; e < 4; e++) a[e] = R[r0 + e][k];
        for (int f = 0; f < 4; f++) b[f] = Cl[k][c0 + f];
        for (int e = 0; e < 4; e++)
            for (int f = 0; f < 4; f++) acc[e][f] = fminf(acc[e][f], a[e] + b[f]);
    }
    for (int e = 0; e < 4; e++)
        for (int f = 0; f < 4; f++) {
            size_t off = (size_t)(bi * 64 + r0 + e) * N + bj * 64 + c0 + f;
            D[off] = fminf(D[off], acc[e][f]);
        }
}

// ---------------- double centering ----------------
__global__ void k_rowmean(const float* __restrict__ D, double* __restrict__ rm) {
    int i = blockIdx.x, t = threadIdx.x;
    const float* dr = D + (size_t)i * N;
    double s = 0;
    for (int j = t; j < N; j += 256) { double d = (double)dr[j]; s += d * d; }
    __shared__ double red[256];
    red[t] = s; __syncthreads();
    for (int off = 128; off; off >>= 1) { if (t < off) red[t] += red[t + off]; __syncthreads(); }
    if (t == 0) rm[i] = red[0] / (double)N;
}

__global__ void k_grand(const double* __restrict__ rm, double* __restrict__ gm) {
    int t = threadIdx.x;
    double s = 0;
    for (int i = t; i < N; i += 256) s += rm[i];
    __shared__ double red[256];
    red[t] = s; __syncthreads();
    for (int off = 128; off; off >>= 1) { if (t < off) red[t] += red[t + off]; __syncthreads(); }
    if (t == 0) gm[0] = red[0] / (double)N;
}

__global__ void k_buildB(const float* __restrict__ D, const double* __restrict__ rm,
                         const double* __restrict__ gm, double* __restrict__ A) {
    int idx = blockIdx.x * 256 + threadIdx.x;
    int i = idx >> 11, j = idx & 2047;
    double d = (double)D[idx];
    A[idx] = -0.5 * (d * d - rm[i] - rm[j] + gm[0]);
}

__global__ void k_setV(float* __restrict__ V) {
    int idx = blockIdx.x * 256 + threadIdx.x;
    int i = idx >> 11, j = idx & 2047;
    V[idx] = (i == j) ? 1.f : 0.f;
}

// ---------------- Jacobi control ----------------
__global__ void k_initflags(unsigned* flags) { flags[0] = 0u; flags[1] = 0u; flags[2] = 0u; }
__global__ void k_sweepctl(unsigned* flags) {
    if (!flags[2]) {
        float mo = __uint_as_float(flags[0]), md = __uint_as_float(flags[1]);
        if (md > 0.f && mo <= 2e-9f * md) { flags[2] = 1u; return; }
        flags[0] = 0u; flags[1] = 0u;
    }
}

// ---------------- task bodies (shared-union via smem base pointer) ----------------
// smem: double[2432] = 19456 B per block.

// V <- V*Q for one 64-row stripe
__device__ __forceinline__ void vapply_task(float* __restrict__ V, const double* __restrict__ qbP,
                                            const int* __restrict__ qp, int rnd, int task, int t,
                                            double* smem) {
    int p = task >> 5, rt = task & 31;
    if (!qp[p]) return;
    float (*Qs)[33] = (float(*)[33])smem;
    float (*Tv)[33] = (float(*)[33])(smem + 528);
    int bi, bj; rr_pairN(rnd, p, NB, bi, bj);
    for (int e = 0; e < 4; e++) {
        int idx = t + e * 256; int a = idx >> 5, c = idx & 31;
        Qs[a][c] = (float)qbP[(size_t)p * 1024 + idx];
    }
    for (int e = 0; e < 8; e++) {
        int idx = t + e * 256; int a = idx >> 5, c = idx & 31;
        int gc = (c < 16) ? bi * 16 + c : bj * 16 + (c - 16);
        Tv[a][c] = V[(size_t)(rt * 64 + a) * N + gc];
    }
    __syncthreads();
    int r0 = (t >> 4) * 4, c0 = (t & 15) * 2;
    float acc[4][2] = {};
    for (int y = 0; y < 32; y++) {
        float q0 = Qs[y][c0], q1 = Qs[y][c0 + 1];
        for (int e = 0; e < 4; e++) {
            float vv = Tv[r0 + e][y];
            acc[e][0] += vv * q0; acc[e][1] += vv * q1;
        }
    }
    for (int e = 0; e < 4; e++)
        for (int f = 0; f < 2; f++) {
            int x = c0 + f;
            int gc = (x < 16) ? bi * 16 + x : bj * 16 + (x - 16);
            V[(size_t)(rt * 64 + r0 + e) * N + gc] = acc[e][f];
        }
}

// local 32x32 Jacobi on pair p of `round` (4 waves, fused two-sided update,
// 2 barriers per micro-round: thread (m1,m2) applies J^T(m1)·[2x2]·J(m2) in regs).
__device__ __forceinline__ void local_task(double* __restrict__ A, double* __restrict__ qb,
                                           int* __restrict__ qfl, unsigned* __restrict__ flags,
                                           int round, int par, int p, int t, double* smem) {
    double* qbC = qb + (size_t)par * (NPAIRS * 1024);
    int* qflC = qfl + par * NPAIRS;
    if (flags[2]) { if (t == 0) qflC[p] = 0; return; }
    double (*M)[33] = (double(*)[33])smem;
    double (*Q)[33] = (double(*)[33])(smem + 1056);
    double* cA = smem + 2112; double* sA = smem + 2128;
    int* ppA = (int*)(smem + 2144); int* qqA = ppA + 16;
    float* rbuf = (float*)(smem + 2160);       // 8 floats: per-wave off/diag maxima
    int* everr = (int*)(smem + 2416);
    int bi, bj; rr_pairN(round, p, NB, bi, bj);

    int rr = t >> 4, cc = t & 15;
    int tm[2] = { bi, bj };
    float offm = 0.f, diagm = 0.f;
    for (int s = 0; s < 4; s++) {
        int u = tm[s >> 1], v = tm[s & 1];
        double val; int dr, dc;
        if (u <= v) { val = A[(size_t)(u * 16 + rr) * N + v * 16 + cc]; dr = (s >> 1) * 16 + rr; dc = (s & 1) * 16 + cc; }
        else        { val = A[(size_t)(v * 16 + rr) * N + u * 16 + cc]; dr = (s >> 1) * 16 + cc; dc = (s & 1) * 16 + rr; }
        M[dr][dc] = val;
        float av = (float)fabs(val);
        if (s == 0 || s == 3) { if (rr == cc) diagm = fmaxf(diagm, av); else offm = fmaxf(offm, av); }
        else offm = fmaxf(offm, av);
    }
    for (int e = 0; e < 4; e++) {
        int idx = t + e * 256; int x = idx >> 5, y = idx & 31;
        Q[x][y] = (x == y) ? 1.0 : 0.0;
    }
    // per-wave shuffle max, then one barrier
    for (int off = 32; off; off >>= 1) {
        offm = fmaxf(offm, __shfl_down(offm, off));
        diagm = fmaxf(diagm, __shfl_down(diagm, off));
    }
    if ((t & 63) == 0) { rbuf[t >> 6] = offm; rbuf[4 + (t >> 6)] = diagm; }
    if (t == 0) *everr = 0;
    __syncthreads();
    float off0 = fmaxf(fmaxf(rbuf[0], rbuf[1]), fmaxf(rbuf[2], rbuf[3]));
    float dmaxf = fmaxf(fmaxf(rbuf[4], rbuf[5]), fmaxf(rbuf[6], rbuf[7]));
    if (t == 0) { atomicMax(flags + 0, __float_as_uint(off0)); atomicMax(flags + 1, __float_as_uint(dmaxf)); }
    double dmax = (double)dmaxf;
    if ((double)off0 <= 1e-9 * dmax) { if (t == 0) qflC[p] = 0; return; }
    double thr = fmax(1e-13 * dmax, 1e-5 * (double)off0);

    int m1 = t >> 4, m2 = t & 15;
    for (int ir = 0; ir < 31; ir++) {
        if (t < 16) {
            int pp, qq; rr_pairN(ir, t, 32, pp, qq);
            double app = M[pp][pp], aqq = M[qq][qq], apq = M[pp][qq];
            double c = 1.0, sn = 0.0;
            if (fabs(apq) > thr) {
                double tau = (aqq - app) / (2.0 * apq);
                double tt2 = ((tau >= 0.0) ? 1.0 : -1.0) / (fabs(tau) + sqrt(1.0 + tau * tau));
                c = 1.0 / sqrt(1.0 + tt2 * tt2);
                sn = tt2 * c;
                *everr = 1;
            }
            ppA[t] = pp; qqA[t] = qq; cA[t] = c; sA[t] = sn;
        }
        __syncthreads();
        // fused two-sided M update: thread (m1,m2) owns the 2x2 block
        {
            double s1 = sA[m1], s2 = sA[m2];
            if (s1 != 0.0 || s2 != 0.0) {
                int p1 = ppA[m1], q1 = qqA[m1];
                int p2 = ppA[m2], q2 = qqA[m2];
                double c1 = cA[m1], c2 = cA[m2];
                double a = M[p1][p2], b = M[p1][q2];
                double cx = M[q1][p2], d = M[q1][q2];
                double a1 = c2 * a - s2 * b,  b1 = s2 * a + c2 * b;
                double c1v = c2 * cx - s2 * d, d1 = s2 * cx + c2 * d;
                M[p1][p2] = c1 * a1 - s1 * c1v; M[p1][q2] = c1 * b1 - s1 * d1;
                M[q1][p2] = s1 * a1 + c1 * c1v; M[q1][q2] = s1 * b1 + c1 * d1;
            }
            // Q col update: Q <- Q*J (512 slots, 2/thread)
            for (int e = 0; e < 2; e++) {
                int slot = t + e * 256; int mm = slot >> 5, k = slot & 31;
                double snq = sA[mm];
                if (snq != 0.0) {
                    int pp = ppA[mm], qq = qqA[mm]; double cq = cA[mm];
                    double qa = Q[k][pp], qb = Q[k][qq];
                    Q[k][pp] = cq * qa - snq * qb; Q[k][qq] = snq * qa + cq * qb;
                }
            }
        }
        __syncthreads();
    }
    int ev = *everr;
    if (t == 0) qflC[p] = ev;
    if (ev) {
        for (int e = 0; e < 4; e++) {
            int idx = t + e * 256; int x = idx >> 5, y = idx & 31;
            qbC[(size_t)p * 1024 + idx] = Q[x][y];
        }
        A[(size_t)(bi * 16 + rr) * N + bi * 16 + cc] = M[rr][cc];
        A[(size_t)(bj * 16 + rr) * N + bj * 16 + cc] = M[16 + rr][16 + cc];
        if (bi <= bj) A[(size_t)(bi * 16 + rr) * N + bj * 16 + cc] = M[rr][16 + cc];
        else          A[(size_t)(bj * 16 + rr) * N + bi * 16 + cc] = M[16 + rr][cc];
    }
}

// tri-apply: A <- Qr^T A Qc on pair tile (pr,pc), fp64 MFMA, canonical storage
__device__ __forceinline__ void tri_task(double* __restrict__ A, const double* __restrict__ qbC,
                                         const int* __restrict__ qflC, int round, int pr, int pc,
                                         int t, double* smem) {
    int fr = qflC[pr], fc = qflC[pc];
    if (!fr && !fc) return;
    double (*T)[33] = (double(*)[33])smem;
    double (*Qb)[33] = (double(*)[33])(smem + 1056);
    int bir, bjr, bic, bjc;
    rr_pairN(round, pr, NB, bir, bjr);
    rr_pairN(round, pc, NB, bic, bjc);
    int rt[2] = { bir, bjr }, ct[2] = { bic, bjc };
    int rr = t >> 4, cc = t & 15;
    if (fr) {
        for (int e = 0; e < 4; e++) {
            int idx = t + e * 256; int a = idx >> 5, b = idx & 31;
            Qb[a][b] = qbC[(size_t)pr * 1024 + idx];
        }
    }
    for (int s = 0; s < 4; s++) {
        int u = rt[s >> 1], v = ct[s & 1];
        if (u <= v) T[(s >> 1) * 16 + rr][(s & 1) * 16 + cc] = A[(size_t)(u * 16 + rr) * N + v * 16 + cc];
        else        T[(s >> 1) * 16 + cc][(s & 1) * 16 + rr] = A[(size_t)(v * 16 + rr) * N + u * 16 + cc];
    }
    __syncthreads();
    int wv = t >> 6, ln = t & 63;
    int i0 = (wv >> 1) * 16, j0 = (wv & 1) * 16;
    int li = ln & 15, lk = ln >> 4;
    if (fr) {
        d4_t d = {0.0, 0.0, 0.0, 0.0};
        #pragma unroll
        for (int y0 = 0; y0 < 32; y0 += 4) {
            double a = Qb[y0 + lk][i0 + li];
            double b = T[y0 + lk][j0 + li];
            d = __builtin_amdgcn_mfma_f64_16x16x4f64(a, b, d, 0, 0, 0);
        }
        __syncthreads();
        #pragma unroll
        for (int v = 0; v < 4; v++) T[i0 + lk * 4 + v][j0 + li] = d[v];
        __syncthreads();
    }
    if (fc) {
        for (int e = 0; e < 4; e++) {
            int idx = t + e * 256; int a = idx >> 5, b = idx & 31;
            Qb[a][b] = qbC[(size_t)pc * 1024 + idx];
        }
        __syncthreads();
        d4_t d = {0.0, 0.0, 0.0, 0.0};
        #pragma unroll
        for (int y0 = 0; y0 < 32; y0 += 4) {
            double a = T[i0 + li][y0 + lk];
            double b = Qb[y0 + lk][j0 + li];
            d = __builtin_amdgcn_mfma_f64_16x16x4f64(a, b, d, 0, 0, 0);
        }
        __syncthreads();
        #pragma unroll
        for (int v = 0; v < 4; v++) T[i0 + lk * 4 + v][j0 + li] = d[v];
        __syncthreads();
    }
    for (int s = 0; s < 4; s++) {
        int u = rt[s >> 1], v = ct[s & 1];
        if (u <= v) A[(size_t)(u * 16 + rr) * N + v * 16 + cc] = T[(s >> 1) * 16 + rr][(s & 1) * 16 + cc];
        else        A[(size_t)(v * 16 + rr) * N + u * 16 + cc] = T[(s >> 1) * 16 + cc][(s & 1) * 16 + rr];
    }
}

// ---------------- pipelined Jacobi kernels ----------------
// round 0 local, standalone prologue
__global__ void __launch_bounds__(256) k_local0(double* __restrict__ A, double* __restrict__ qb,
                                                int* __restrict__ qfl, unsigned* __restrict__ flags) {
    __shared__ double smem[2432];
    local_task(A, qb, qfl, flags, 0, 0, (int)blockIdx.x, (int)threadIdx.x, smem);
}

// fused single launch per round:
//   blocks 0..63: [inlined critical tri(round) for this next-pair] then local(nextRound)
//   blocks 64..64+NTRI-1: tri_rest(round) (critical tasks excluded)
//   remaining: V-apply(round)
__global__ void __launch_bounds__(256) k_fused(double* __restrict__ A, float* __restrict__ V,
                                               double* __restrict__ qb, int* __restrict__ qfl,
                                               unsigned* __restrict__ flags,
                                               int round, int par, int nextRound, int nextPar,
                                               int nextValid) {
    __shared__ double smem[2432];
    int t = threadIdx.x, blk = blockIdx.x;
    if (blk < NPAIRS) {
        if (!flags[2]) {
            int u, v; rr_pairN(nextRound, blk, NB, u, v);
            int a = rr_pidx(round, u), b = rr_pidx(round, v);
            int pr = min(a, b), pc = max(a, b);
            tri_task(A, qb + (size_t)par * (NPAIRS * 1024), qfl + par * NPAIRS,
                     round, pr, pc, t, smem);
            __syncthreads();
        }
        if (nextValid) local_task(A, qb, qfl, flags, nextRound, nextPar, blk, t, smem);
    } else if (blk < NPAIRS + NTRI) {
        if (flags[2]) return;
        int task = blk - NPAIRS;
        int pr = 0, rem = task;
        while (rem >= 63 - pr) { rem -= 63 - pr; pr++; }
        int pc = pr + 1 + rem;
        int bir, bjr, bic, bjc;
        rr_pairN(round, pr, NB, bir, bjr);
        rr_pairN(round, pc, NB, bic, bjc);
        #pragma unroll
        for (int s = 0; s < 4; s++) {
            int tu = (s >> 1) ? bjr : bir, tv = (s & 1) ? bjc : bic;
            if (rr_partner(nextRound, tu) == tv) return;   // critical: handled in local blocks
        }
        tri_task(A, qb + (size_t)par * (NPAIRS * 1024), qfl + par * NPAIRS, round, pr, pc, t, smem);
    } else {
        if (flags[2]) return;
        vapply_task(V, qb + (size_t)par * (NPAIRS * 1024), qfl + par * NPAIRS,
                    round, blk - NPAIRS - NTRI, t, smem);
    }
}

// ---------------- epilogue ----------------
__global__ void k_lambda(const double* __restrict__ A, double* __restrict__ lam) {
    int i = blockIdx.x * 256 + threadIdx.x;
    if (i < N) lam[i] = A[(size_t)i * N + i];
}

__global__ void __launch_bounds__(1024) k_sort(const double* __restrict__ lam,
                                               double* __restrict__ lams, int* __restrict__ order) {
    __shared__ double v[2048]; __shared__ int ix[2048];
    int t = threadIdx.x;
    v[t] = lam[t]; v[t + 1024] = lam[t + 1024];
    ix[t] = t; ix[t + 1024] = t + 1024;
    __syncthreads();
    for (int k = 2; k <= 2048; k <<= 1) {
        for (int j = k >> 1; j > 0; j >>= 1) {
            int l = ((t & ~(j - 1)) << 1) | (t & (j - 1));
            int partner = l | j;
            double va = v[l], vb = v[partner]; int ia = ix[l], ib = ix[partner];
            bool before = (va > vb) || (va == vb && ia < ib);
            bool asc = ((l & k) == 0);
            bool doSwap = asc ? (!before) : before;
            if (doSwap) { v[l] = vb; v[partner] = va; ix[l] = ib; ix[partner] = ia; }
            __syncthreads();
        }
    }
    lams[t] = v[t]; lams[t + 1024] = v[t + 1024];
    order[t] = ix[t]; order[t + 1024] = ix[t + 1024];
}

__global__ void k_out(const float* __restrict__ Vm, const double* __restrict__ lams,
                      const int* __restrict__ order, float* __restrict__ out) {
    int c = blockIdx.x, t = threadIdx.x;
    int col = order[c];
    __shared__ float rv[256]; __shared__ int ri[256];
    float bv = -1.f; int bidx = N;
    for (int i = t; i < N; i += 256) {
        float av = fabsf(Vm[(size_t)i * N + col]);
        if (av > bv || (av == bv && i < bidx)) { bv = av; bidx = i; }
    }
    rv[t] = bv; ri[t] = bidx;
    __syncthreads();
    for (int off = 128; off; off >>= 1) {
        if (t < off) {
            if (rv[t + off] > rv[t] || (rv[t + off] == rv[t] && ri[t + off] < ri[t])) {
                rv[t] = rv[t + off]; ri[t] = ri[t + off];
            }
        }
        __syncthreads();
    }
    float sv = Vm[(size_t)ri[0] * N + col];
    float s = (sv > 0.f) ? 1.f : ((sv < 0.f) ? -1.f : 0.f);
    double lv = lams[c];
    float f = s * (float)sqrt(lv > 0.0 ? lv : 0.0);
    for (int i = t; i < N; i += 256) out[(size_t)i * NC + c] = Vm[(size_t)i * N + col] * f;
}

extern "C" void kernel_launch(void* const* d_in, const int* in_sizes, int n_in,
                              void* d_out, int out_size, void* d_ws, size_t ws_size,
                              hipStream_t stream) {
    (void)in_sizes; (void)n_in; (void)out_size; (void)ws_size;
    const float* X = (const float*)d_in[0];
    float* out = (float*)d_out;

    double* rm  = (double*)d_ws;                 // N
    double* gm  = rm + N;                        // 1 (+7 pad)
    double* lam = gm + 8;                        // N
    double* lams= lam + N;                       // N
    double* A   = lams + N;                      // N*N fp64
    double* qb  = A + (size_t)N * N;             // 2 * NPAIRS*1024 fp64 (double-buffered)
    float* Dg   = (float*)(qb + 2 * (size_t)NPAIRS * 1024); // N*N f32
    float* Vm   = Dg + (size_t)N * N;            // N*N f32
    float* sq   = Vm + (size_t)N * N;            // N
    int* order  = (int*)(sq + N);                // N
    int* qfl    = order + N;                     // 2 * NPAIRS
    unsigned* flags = (unsigned*)(qfl + 2 * NPAIRS); // 3
    float* dist = (float*)A;                     // alias: dist dies before A is born

    // 1. pairwise distances
    k_rowsq<<<N / 4, 256, 0, stream>>>(X, sq);
    k_dist<<<dim3(32, 32), 256, 0, stream>>>(X, sq, dist);

    // 2. KNN graph
    k_knn<<<N, 256, 0, stream>>>(dist, Dg);
    k_symdiag<<<(N * N) / 256, 256, 0, stream>>>(Dg);

    // 3. blocked Floyd-Warshall
    for (int kb = 0; kb < N / 64; kb++) {
        k_fw12<<<63, 256, 0, stream>>>(Dg, kb);
        k_fw3<<<dim3(32, 32), 256, 0, stream>>>(Dg, kb);
    }

    // 4. double centering -> B (fp64)
    k_rowmean<<<N, 256, 0, stream>>>(Dg, rm);
    k_grand<<<1, 256, 0, stream>>>(rm, gm);
    k_buildB<<<(N * N) / 256, 256, 0, stream>>>(Dg, rm, gm, A);
    k_setV<<<(N * N) / 256, 256, 0, stream>>>(Vm);
    k_initflags<<<1, 1, 0, stream>>>(flags);

    // 5. pipelined two-sided block Jacobi, ONE launch per round:
    //    local(0) prologue; per round g: fused{ critTri(g)+local(g+1) || tri_rest(g) || V(g) }.
    const int G = NSWEEPS * (NB - 1);
    k_local0<<<NPAIRS, 256, 0, stream>>>(A, qb, qfl, flags);
    for (int g = 0; g < G; g++) {
        int round = g % (NB - 1), par = g & 1;
        int nr = (g + 1) % (NB - 1), npar = (g + 1) & 1;
        int nv = (g + 1 < G) ? 1 : 0;
        if (((g + 1) % (NB - 1)) == 0)
            k_sweepctl<<<1, 1, 0, stream>>>(flags);
        k_fused<<<NPAIRS + NTRI + NVS, 256, 0, stream>>>(A, Vm, qb, qfl, flags,
                                                         round, par, nr, npar, nv);
    }

    // 6. sort eigenvalues, sign-fix, scale, write output
    k_lambda<<<N / 256, 256, 0, stream>>>(A, lam);
    k_sort<<<1, 1024, 0, stream>>>(lam, lams, order);
    k_out<<<NC, 256, 0, stream>>>(Vm, lams, order, out);
}

// Round 10
// 61349.835 us; speedup vs baseline: 2.1607x; 1.0601x over previous
//
#include <hip/hip_runtime.h>
#include <math.h>

#define N 2048
#define DIMS 784
#define BIGV 1.0e6f
#define NC 784

// two-sided block Jacobi config: 128 teams of width 16, 32x32 local tiles
#define NB 128
#define NPAIRS 64
#define NSWEEPS 18
#define NTRI 2016      // 64*63/2 upper-tri pair tiles
#define NVS  2048      // 64 pairs * 32 V row-stripes
#define NTRIB 1008     // tri blocks (2 tasks each)
#define NVB  1024      // V blocks (2 stripes each)

typedef __attribute__((ext_vector_type(4))) double d4_t;

// round-robin pairing over nteams: round r in [0,nteams-1), pair m in [0,nteams/2)
__device__ __forceinline__ void rr_pairN(int r, int m, int nteams, int& bi, int& bj) {
    int n1 = nteams - 1;
    if (m == 0) { bi = n1; bj = r % n1; }
    else { bi = (r + m) % n1; bj = (r - m + n1) % n1; }
}

// pair index of team x in round r (NB teams)
__device__ __forceinline__ int rr_pidx(int r, int x) {
    const int n1 = NB - 1;
    if (x == n1) return 0;
    int m = (x - r) % n1; if (m < 0) m += n1;
    if (m == 0) return 0;
    return (m <= n1 / 2) ? m : n1 - m;
}
// partner team of x in round r
__device__ __forceinline__ int rr_partner(int r, int x) {
    const int n1 = NB - 1;
    if (x == n1) return r % n1;
    int m = (x - r) % n1; if (m < 0) m += n1;
    if (m == 0) return n1;
    if (m <= n1 / 2) return (r - m + n1) % n1;
    int m2 = n1 - m; return (r + m2) % n1;
}

// A is stored CANONICALLY: 16x16 team-sub-block (u,v) valid only at u<=v.

// ---------------- distances ----------------
__global__ void k_rowsq(const float* __restrict__ X, float* __restrict__ sq) {
    int wave = threadIdx.x >> 6, lane = threadIdx.x & 63;
    int row = blockIdx.x * 4 + wave;
    const float* xr = X + (size_t)row * DIMS;
    float s = 0.f;
    for (int k = lane; k < DIMS; k += 64) { float v = xr[k]; s += v * v; }
    for (int off = 32; off; off >>= 1) s += __shfl_down(s, off);
    if (lane == 0) sq[row] = s;
}

__global__ void __launch_bounds__(256) k_dist(const float* __restrict__ X,
                                              const float* __restrict__ sq,
                                              float* __restrict__ out) {
    __shared__ float As[64][17], Bs[64][17];
    int ti = blockIdx.y, tj = blockIdx.x, t = threadIdx.x;
    int tx = t & 15, ty = t >> 4;
    float acc[4][4] = {};
    for (int k0 = 0; k0 < DIMS; k0 += 16) {
        for (int e = 0; e < 4; e++) {
            int idx = t + e * 256; int r = idx >> 4, c = idx & 15;
            As[r][c] = X[(size_t)(ti * 64 + r) * DIMS + k0 + c];
            Bs[r][c] = X[(size_t)(tj * 64 + r) * DIMS + k0 + c];
        }
        __syncthreads();
        for (int k = 0; k < 16; k++) {
            float a[4], b[4];
            for (int e = 0; e < 4; e++) a[e] = As[ty * 4 + e][k];
            for (int f = 0; f < 4; f++) b[f] = Bs[tx * 4 + f][k];
            for (int e = 0; e < 4; e++)
                for (int f = 0; f < 4; f++) acc[e][f] += a[e] * b[f];
        }
        __syncthreads();
    }
    for (int e = 0; e < 4; e++)
        for (int f = 0; f < 4; f++) {
            int gi = ti * 64 + ty * 4 + e, gj = tj * 64 + tx * 4 + f;
            float d2 = sq[gi] + sq[gj] - 2.f * acc[e][f];
            out[(size_t)gi * N + gj] = sqrtf(fmaxf(d2, 0.f));
        }
}

// ---------------- KNN graph ----------------
__global__ void k_knn(const float* __restrict__ dist, float* __restrict__ G) {
    int i = blockIdx.x, t = threadIdx.x;
    float bv[6]; int bidx[6];
    for (int k = 0; k < 6; k++) { bv[k] = 3.4e38f; bidx[k] = N; }
    const float* dr = dist + (size_t)i * N;
    for (int j = t; j < N; j += 256) {
        float v = dr[j];
        bool ins = (v < bv[5]) || (v == bv[5] && j < bidx[5]);
        if (ins) {
            int k = 5;
            while (k > 0) {
                bool mv = (v < bv[k - 1]) || (v == bv[k - 1] && j < bidx[k - 1]);
                if (!mv) break;
                bv[k] = bv[k - 1]; bidx[k] = bidx[k - 1]; k--;
            }
            bv[k] = v; bidx[k] = j;
        }
    }
    __shared__ float lv[256][6]; __shared__ int li[256][6];
    for (int k = 0; k < 6; k++) { lv[t][k] = bv[k]; li[t][k] = bidx[k]; }
    __syncthreads();
    for (int off = 128; off >= 1; off >>= 1) {
        if (t < off) {
            float av[6], cv[6]; int ai[6], ci[6];
            for (int k = 0; k < 6; k++) { av[k] = lv[t][k]; ai[k] = li[t][k]; cv[k] = lv[t + off][k]; ci[k] = li[t + off][k]; }
            float mv[6]; int mi[6]; int pa = 0, pb = 0;
            for (int k = 0; k < 6; k++) {
                bool ta;
                if (pa >= 6) ta = false;
                else if (pb >= 6) ta = true;
                else ta = (av[pa] < cv[pb]) || (av[pa] == cv[pb] && ai[pa] < ci[pb]);
                if (ta) { mv[k] = av[pa]; mi[k] = ai[pa]; pa++; }
                else    { mv[k] = cv[pb]; mi[k] = ci[pb]; pb++; }
            }
            for (int k = 0; k < 6; k++) { lv[t][k] = mv[k]; li[t][k] = mi[k]; }
        }
        __syncthreads();
    }
    float sv[6]; int si[6];
    for (int k = 0; k < 6; k++) { sv[k] = lv[0][k]; si[k] = li[0][k]; }
    for (int j = t; j < N; j += 256) {
        float val = BIGV;
        for (int k = 0; k < 6; k++) if (j == si[k]) val = sv[k];
        G[(size_t)i * N + j] = val;
    }
}

__global__ void k_symdiag(float* __restrict__ G) {
    int idx = blockIdx.x * 256 + threadIdx.x;
    int i = idx >> 11, j = idx & 2047;
    if (i == j) { G[idx] = 0.f; return; }
    if (j > i) {
        float a = G[(size_t)i * N + j], b = G[(size_t)j * N + i];
        float m = fminf(a, b);
        G[(size_t)i * N + j] = m; G[(size_t)j * N + i] = m;
    }
}

// ---------------- blocked Floyd-Warshall ----------------
__global__ void __launch_bounds__(256) k_fw12(float* __restrict__ D, int kb) {
    __shared__ float KK[64][65], C[64][65];
    int bx = blockIdx.x, t = threadIdx.x;
    for (int e = 0; e < 16; e++) { int idx = t + e * 256; int r = idx >> 6, c = idx & 63;
        KK[r][c] = D[(size_t)(kb * 64 + r) * N + kb * 64 + c]; }
    __syncthreads();
    int r0 = t >> 2, c0 = (t & 3) * 16;
    for (int k = 0; k < 64; k++) {
        float dk = KK[r0][k];
        for (int c = 0; c < 16; c++) KK[r0][c0 + c] = fminf(KK[r0][c0 + c], dk + KK[k][c0 + c]);
        __syncthreads();
    }
    if (bx == 62) {
        for (int e = 0; e < 16; e++) { int idx = t + e * 256; int r = idx >> 6, c = idx & 63;
            D[(size_t)(kb * 64 + r) * N + kb * 64 + c] = KK[r][c]; }
        return;
    }
    bool rowstripe = bx < 31;
    int o = rowstripe ? bx : bx - 31;
    o += (o >= kb) ? 1 : 0;
    int baseR = rowstripe ? kb : o;
    int baseC = rowstripe ? o : kb;
    for (int e = 0; e < 16; e++) { int idx = t + e * 256; int r = idx >> 6, c = idx & 63;
        C[r][c] = D[(size_t)(baseR * 64 + r) * N + baseC * 64 + c]; }
    __syncthreads();
    if (rowstripe) {
        for (int k = 0; k < 64; k++) {
            float dk = KK[r0][k];
            for (int c = 0; c < 16; c++) C[r0][c0 + c] = fminf(C[r0][c0 + c], dk + C[k][c0 + c]);
            __syncthreads();
        }
    } else {
        for (int k = 0; k < 64; k++) {
            float dk = C[r0][k];
            for (int c = 0; c < 16; c++) C[r0][c0 + c] = fminf(C[r0][c0 + c], dk + KK[k][c0 + c]);
            __syncthreads();
        }
    }
    for (int e = 0; e < 16; e++) { int idx = t + e * 256; int r = idx >> 6, c = idx & 63;
        D[(size_t)(baseR * 64 + r) * N + baseC * 64 + c] = C[r][c]; }
}

__global__ void __launch_bounds__(256) k_fw3(float* __restrict__ D, int kb) {
    int bi = blockIdx.y, bj = blockIdx.x;
    if (bi == kb || bj == kb) return;
    __shared__ float R[64][65], Cl[64][65];
    int t = threadIdx.x;
    for (int e = 0; e < 16; e++) { int idx = t + e * 256; int r = idx >> 6, c = idx & 63;
        R[r][c]  = D[(size_t)(bi * 64 + r) * N + kb * 64 + c];
        Cl[r][c] = D[(size_t)(kb * 64 + r) * N + bj * 64 + c]; }
    __syncthreads();
    int r0 = (t >> 4) * 4, c0 = (t & 15) * 4;
    float acc[4][4];
    for (int e = 0; e < 4; e++) for (int f = 0; f < 4; f++) acc[e][f] = 3.4e38f;
    for (int k = 0; k < 64; k++) {
        float a[4], b[4];
        for (int e = 0; e < 4; e++) a[e] = R[r0 + e][k];
        for (int f = 0; f < 4; f++) b[f] = Cl[k][c0 + f];
        for (int e = 0; e < 4; e++)
            for (int f = 0; f < 4; f++) acc[e][f] = fminf(acc[e][f], a[e] + b[f]);
    }
    for (int e = 0; e < 4; e++)
        for (int f = 0; f < 4; f++) {
            size_t off = (size_t)(bi * 64 + r0 + e) * N + bj * 64 + c0 + f;
            D[off] = fminf(D[off], acc[e][f]);
        }
}

// ---------------- double centering ----------------
__global__ void k_rowmean(const float* __restrict__ D, double* __restrict__ rm) {
    int i = blockIdx.x, t = threadIdx.x;
    const float* dr = D + (size_t)i * N;
    double s = 0;
    for (int j = t; j < N; j += 256) { double d = (double)dr[j]; s += d * d; }
    __shared__ double red[256];
    red[t] = s; __syncthreads();
    for (int off = 128; off; off >>= 1) { if (t < off) red[t] += red[t + off]; __syncthreads(); }
    if (t == 0) rm[i] = red[0] / (double)N;
}

__global__ void k_grand(const double* __restrict__ rm, double* __restrict__ gm) {
    int t = threadIdx.x;
    double s = 0;
    for (int i = t; i < N; i += 256) s += rm[i];
    __shared__ double red[256];
    red[t] = s; __syncthreads();
    for (int off = 128; off; off >>= 1) { if (t < off) red[t] += red[t + off]; __syncthreads(); }
    if (t == 0) gm[0] = red[0] / (double)N;
}

__global__ void k_buildB(const float* __restrict__ D, const double* __restrict__ rm,
                         const double* __restrict__ gm, double* __restrict__ A) {
    int idx = blockIdx.x * 256 + threadIdx.x;
    int i = idx >> 11, j = idx & 2047;
    double d = (double)D[idx];
    A[idx] = -0.5 * (d * d - rm[i] - rm[j] + gm[0]);
}

__global__ void k_setV(float* __restrict__ V) {
    int idx = blockIdx.x * 256 + threadIdx.x;
    int i = idx >> 11, j = idx & 2047;
    V[idx] = (i == j) ? 1.f : 0.f;
}

// ---------------- Jacobi control ----------------
__global__ void k_initflags(unsigned* flags) { flags[0] = 0u; flags[1] = 0u; flags[2] = 0u; }
__global__ void k_sweepctl(unsigned* flags) {
    if (!flags[2]) {
        float mo = __uint_as_float(flags[0]), md = __uint_as_float(flags[1]);
        if (md > 0.f && mo <= 2e-9f * md) { flags[2] = 1u; return; }
        flags[0] = 0u; flags[1] = 0u;
    }
}

// ---------------- task bodies (shared-union via smem base pointer) ----------------
// smem: double[2432] = 19456 B per block.

// V <- V*Q for one 64-row stripe
__device__ __forceinline__ void vapply_task(float* __restrict__ V, const double* __restrict__ qbP,
                                            const int* __restrict__ qp, int rnd, int task, int t,
                                            double* smem) {
    int p = task >> 5, rt = task & 31;
    if (!qp[p]) return;
    float (*Qs)[33] = (float(*)[33])smem;
    float (*Tv)[33] = (float(*)[33])(smem + 528);
    int bi, bj; rr_pairN(rnd, p, NB, bi, bj);
    for (int e = 0; e < 4; e++) {
        int idx = t + e * 256; int a = idx >> 5, c = idx & 31;
        Qs[a][c] = (float)qbP[(size_t)p * 1024 + idx];
    }
    for (int e = 0; e < 8; e++) {
        int idx = t + e * 256; int a = idx >> 5, c = idx & 31;
        int gc = (c < 16) ? bi * 16 + c : bj * 16 + (c - 16);
        Tv[a][c] = V[(size_t)(rt * 64 + a) * N + gc];
    }
    __syncthreads();
    int r0 = (t >> 4) * 4, c0 = (t & 15) * 2;
    float acc[4][2] = {};
    for (int y = 0; y < 32; y++) {
        float q0 = Qs[y][c0], q1 = Qs[y][c0 + 1];
        for (int e = 0; e < 4; e++) {
            float vv = Tv[r0 + e][y];
            acc[e][0] += vv * q0; acc[e][1] += vv * q1;
        }
    }
    for (int e = 0; e < 4; e++)
        for (int f = 0; f < 2; f++) {
            int x = c0 + f;
            int gc = (x < 16) ? bi * 16 + x : bj * 16 + (x - 16);
            V[(size_t)(rt * 64 + r0 + e) * N + gc] = acc[e][f];
        }
}

// local 32x32 Jacobi on pair p of `round` (4 waves, fused two-sided update,
// 2 barriers per micro-round: thread (m1,m2) applies J^T(m1)·[2x2]·J(m2) in regs).
__device__ __forceinline__ void local_task(double* __restrict__ A, double* __restrict__ qb,
                                           int* __restrict__ qfl, unsigned* __restrict__ flags,
                                           int round, int par, int p, int t, double* smem) {
    double* qbC = qb + (size_t)par * (NPAIRS * 1024);
    int* qflC = qfl + par * NPAIRS;
    if (flags[2]) { if (t == 0) qflC[p] = 0; return; }
    double (*M)[33] = (double(*)[33])smem;
    double (*Q)[33] = (double(*)[33])(smem + 1056);
    double* cA = smem + 2112; double* sA = smem + 2128;
    int* ppA = (int*)(smem + 2144); int* qqA = ppA + 16;
    float* rbuf = (float*)(smem + 2160);       // 8 floats: per-wave off/diag maxima
    int* everr = (int*)(smem + 2416);
    int bi, bj; rr_pairN(round, p, NB, bi, bj);

    int rr = t >> 4, cc = t & 15;
    int tm[2] = { bi, bj };
    float offm = 0.f, diagm = 0.f;
    for (int s = 0; s < 4; s++) {
        int u = tm[s >> 1], v = tm[s & 1];
        double val; int dr, dc;
        if (u <= v) { val = A[(size_t)(u * 16 + rr) * N + v * 16 + cc]; dr = (s >> 1) * 16 + rr; dc = (s & 1) * 16 + cc; }
        else        { val = A[(size_t)(v * 16 + rr) * N + u * 16 + cc]; dr = (s >> 1) * 16 + cc; dc = (s & 1) * 16 + rr; }
        M[dr][dc] = val;
        float av = (float)fabs(val);
        if (s == 0 || s == 3) { if (rr == cc) diagm = fmaxf(diagm, av); else offm = fmaxf(offm, av); }
        else offm = fmaxf(offm, av);
    }
    for (int e = 0; e < 4; e++) {
        int idx = t + e * 256; int x = idx >> 5, y = idx & 31;
        Q[x][y] = (x == y) ? 1.0 : 0.0;
    }
    // per-wave shuffle max, then one barrier
    for (int off = 32; off; off >>= 1) {
        offm = fmaxf(offm, __shfl_down(offm, off));
        diagm = fmaxf(diagm, __shfl_down(diagm, off));
    }
    if ((t & 63) == 0) { rbuf[t >> 6] = offm; rbuf[4 + (t >> 6)] = diagm; }
    if (t == 0) *everr = 0;
    __syncthreads();
    float off0 = fmaxf(fmaxf(rbuf[0], rbuf[1]), fmaxf(rbuf[2], rbuf[3]));
    float dmaxf = fmaxf(fmaxf(rbuf[4], rbuf[5]), fmaxf(rbuf[6], rbuf[7]));
    if (t == 0) { atomicMax(flags + 0, __float_as_uint(off0)); atomicMax(flags + 1, __float_as_uint(dmaxf)); }
    double dmax = (double)dmaxf;
    if ((double)off0 <= 1e-9 * dmax) { if (t == 0) qflC[p] = 0; return; }
    double thr = fmax(1e-13 * dmax, 1e-5 * (double)off0);

    int m1 = t >> 4, m2 = t & 15;
    for (int ir = 0; ir < 31; ir++) {
        if (t < 16) {
            int pp, qq; rr_pairN(ir, t, 32, pp, qq);
            double app = M[pp][pp], aqq = M[qq][qq], apq = M[pp][qq];
            double c = 1.0, sn = 0.0;
            if (fabs(apq) > thr) {
                double tau = (aqq - app) / (2.0 * apq);
                double tt2 = ((tau >= 0.0) ? 1.0 : -1.0) / (fabs(tau) + sqrt(1.0 + tau * tau));
                c = 1.0 / sqrt(1.0 + tt2 * tt2);
                sn = tt2 * c;
                *everr = 1;
            }
            ppA[t] = pp; qqA[t] = qq; cA[t] = c; sA[t] = sn;
        }
        __syncthreads();
        // fused two-sided M update: thread (m1,m2) owns the 2x2 block
        {
            double s1 = sA[m1], s2 = sA[m2];
            if (s1 != 0.0 || s2 != 0.0) {
                int p1 = ppA[m1], q1 = qqA[m1];
                int p2 = ppA[m2], q2 = qqA[m2];
                double c1 = cA[m1], c2 = cA[m2];
                double a = M[p1][p2], b = M[p1][q2];
                double cx = M[q1][p2], d = M[q1][q2];
                double a1 = c2 * a - s2 * b,  b1 = s2 * a + c2 * b;
                double c1v = c2 * cx - s2 * d, d1 = s2 * cx + c2 * d;
                M[p1][p2] = c1 * a1 - s1 * c1v; M[p1][q2] = c1 * b1 - s1 * d1;
                M[q1][p2] = s1 * a1 + c1 * c1v; M[q1][q2] = s1 * b1 + c1 * d1;
            }
            // Q col update: Q <- Q*J (512 slots, 2/thread)
            for (int e = 0; e < 2; e++) {
                int slot = t + e * 256; int mm = slot >> 5, k = slot & 31;
                double snq = sA[mm];
                if (snq != 0.0) {
                    int pp = ppA[mm], qq = qqA[mm]; double cq = cA[mm];
                    double qa = Q[k][pp], qb = Q[k][qq];
                    Q[k][pp] = cq * qa - snq * qb; Q[k][qq] = snq * qa + cq * qb;
                }
            }
        }
        __syncthreads();
    }
    int ev = *everr;
    if (t == 0) qflC[p] = ev;
    if (ev) {
        for (int e = 0; e < 4; e++) {
            int idx = t + e * 256; int x = idx >> 5, y = idx & 31;
            qbC[(size_t)p * 1024 + idx] = Q[x][y];
        }
        A[(size_t)(bi * 16 + rr) * N + bi * 16 + cc] = M[rr][cc];
        A[(size_t)(bj * 16 + rr) * N + bj * 16 + cc] = M[16 + rr][16 + cc];
        if (bi <= bj) A[(size_t)(bi * 16 + rr) * N + bj * 16 + cc] = M[rr][16 + cc];
        else          A[(size_t)(bj * 16 + rr) * N + bi * 16 + cc] = M[16 + rr][cc];
    }
}

// tri-apply: A <- Qr^T A Qc on pair tile (pr,pc), fp64 MFMA, canonical storage
__device__ __forceinline__ void tri_task(double* __restrict__ A, const double* __restrict__ qbC,
                                         const int* __restrict__ qflC, int round, int pr, int pc,
                                         int t, double* smem) {
    int fr = qflC[pr], fc = qflC[pc];
    if (!fr && !fc) return;
    double (*T)[33] = (double(*)[33])smem;
    double (*Qb)[33] = (double(*)[33])(smem + 1056);
    int bir, bjr, bic, bjc;
    rr_pairN(round, pr, NB, bir, bjr);
    rr_pairN(round, pc, NB, bic, bjc);
    int rt[2] = { bir, bjr }, ct[2] = { bic, bjc };
    int rr = t >> 4, cc = t & 15;
    if (fr) {
        for (int e = 0; e < 4; e++) {
            int idx = t + e * 256; int a = idx >> 5, b = idx & 31;
            Qb[a][b] = qbC[(size_t)pr * 1024 + idx];
        }
    }
    for (int s = 0; s < 4; s++) {
        int u = rt[s >> 1], v = ct[s & 1];
        if (u <= v) T[(s >> 1) * 16 + rr][(s & 1) * 16 + cc] = A[(size_t)(u * 16 + rr) * N + v * 16 + cc];
        else        T[(s >> 1) * 16 + cc][(s & 1) * 16 + rr] = A[(size_t)(v * 16 + rr) * N + u * 16 + cc];
    }
    __syncthreads();
    int wv = t >> 6, ln = t & 63;
    int i0 = (wv >> 1) * 16, j0 = (wv & 1) * 16;
    int li = ln & 15, lk = ln >> 4;
    if (fr) {
        d4_t d = {0.0, 0.0, 0.0, 0.0};
        #pragma unroll
        for (int y0 = 0; y0 < 32; y0 += 4) {
            double a = Qb[y0 + lk][i0 + li];
            double b = T[y0 + lk][j0 + li];
            d = __builtin_amdgcn_mfma_f64_16x16x4f64(a, b, d, 0, 0, 0);
        }
        __syncthreads();
        #pragma unroll
        for (int v = 0; v < 4; v++) T[i0 + lk * 4 + v][j0 + li] = d[v];
        __syncthreads();
    }
    if (fc) {
        for (int e = 0; e < 4; e++) {
            int idx = t + e * 256; int a = idx >> 5, b = idx & 31;
            Qb[a][b] = qbC[(size_t)pc * 1024 + idx];
        }
        __syncthreads();
        d4_t d = {0.0, 0.0, 0.0, 0.0};
        #pragma unroll
        for (int y0 = 0; y0 < 32; y0 += 4) {
            double a = T[i0 + li][y0 + lk];
            double b = Qb[y0 + lk][j0 + li];
            d = __builtin_amdgcn_mfma_f64_16x16x4f64(a, b, d, 0, 0, 0);
        }
        __syncthreads();
        #pragma unroll
        for (int v = 0; v < 4; v++) T[i0 + lk * 4 + v][j0 + li] = d[v];
        __syncthreads();
    }
    for (int s = 0; s < 4; s++) {
        int u = rt[s >> 1], v = ct[s & 1];
        if (u <= v) A[(size_t)(u * 16 + rr) * N + v * 16 + cc] = T[(s >> 1) * 16 + rr][(s & 1) * 16 + cc];
        else        A[(size_t)(v * 16 + rr) * N + u * 16 + cc] = T[(s >> 1) * 16 + cc][(s & 1) * 16 + rr];
    }
}

// ---------------- pipelined Jacobi kernels ----------------
// round 0 local, standalone prologue
__global__ void __launch_bounds__(256) k_local0(double* __restrict__ A, double* __restrict__ qb,
                                                int* __restrict__ qfl, unsigned* __restrict__ flags) {
    __shared__ double smem[2432];
    local_task(A, qb, qfl, flags, 0, 0, (int)blockIdx.x, (int)threadIdx.x, smem);
}

// fused single launch per round (compact grid, one co-residency wave):
//   blocks 0..63: setprio(1) { critical tri(round) ; local(nextRound) } setprio(0)
//   blocks 64..64+NTRIB-1: 2 tri_rest(round) tasks each (critical excluded)
//   remaining NVB blocks: 2 V-apply(round) stripes each
__global__ void __launch_bounds__(256) k_fused(double* __restrict__ A, float* __restrict__ V,
                                               double* __restrict__ qb, int* __restrict__ qfl,
                                               unsigned* __restrict__ flags,
                                               int round, int par, int nextRound, int nextPar,
                                               int nextValid) {
    __shared__ double smem[2432];
    int t = threadIdx.x, blk = blockIdx.x;
    if (blk < NPAIRS) {
        __builtin_amdgcn_s_setprio(1);     // critical-path blocks: favor on CU scheduler
        if (!flags[2]) {
            int u, v; rr_pairN(nextRound, blk, NB, u, v);
            int a = rr_pidx(round, u), b = rr_pidx(round, v);
            int pr = min(a, b), pc = max(a, b);
            tri_task(A, qb + (size_t)par * (NPAIRS * 1024), qfl + par * NPAIRS,
                     round, pr, pc, t, smem);
            __syncthreads();
        }
        if (nextValid) local_task(A, qb, qfl, flags, nextRound, nextPar, blk, t, smem);
        __builtin_amdgcn_s_setprio(0);
    } else if (blk < NPAIRS + NTRIB) {
        if (flags[2]) return;
        for (int task = blk - NPAIRS; task < NTRI; task += NTRIB) {
            int pr = 0, rem = task;
            while (rem >= 63 - pr) { rem -= 63 - pr; pr++; }
            int pc = pr + 1 + rem;
            int bir, bjr, bic, bjc;
            rr_pairN(round, pr, NB, bir, bjr);
            rr_pairN(round, pc, NB, bic, bjc);
            bool crit = false;
            #pragma unroll
            for (int s = 0; s < 4; s++) {
                int tu = (s >> 1) ? bjr : bir, tv = (s & 1) ? bjc : bic;
                if (rr_partner(nextRound, tu) == tv) crit = true;  // handled by local blocks
            }
            if (!crit)
                tri_task(A, qb + (size_t)par * (NPAIRS * 1024), qfl + par * NPAIRS,
                         round, pr, pc, t, smem);
            __syncthreads();   // protect smem reuse between the two tasks
        }
    } else {
        if (flags[2]) return;
        for (int v = blk - NPAIRS - NTRIB; v < NVS; v += NVB) {
            vapply_task(V, qb + (size_t)par * (NPAIRS * 1024), qfl + par * NPAIRS,
                        round, v, t, smem);
            __syncthreads();   // protect smem reuse between the two stripes
        }
    }
}

// ---------------- epilogue ----------------
__global__ void k_lambda(const double* __restrict__ A, double* __restrict__ lam) {
    int i = blockIdx.x * 256 + threadIdx.x;
    if (i < N) lam[i] = A[(size_t)i * N + i];
}

__global__ void __launch_bounds__(1024) k_sort(const double* __restrict__ lam,
                                               double* __restrict__ lams, int* __restrict__ order) {
    __shared__ double v[2048]; __shared__ int ix[2048];
    int t = threadIdx.x;
    v[t] = lam[t]; v[t + 1024] = lam[t + 1024];
    ix[t] = t; ix[t + 1024] = t + 1024;
    __syncthreads();
    for (int k = 2; k <= 2048; k <<= 1) {
        for (int j = k >> 1; j > 0; j >>= 1) {
            int l = ((t & ~(j - 1)) << 1) | (t & (j - 1));
            int partner = l | j;
            double va = v[l], vb = v[partner]; int ia = ix[l], ib = ix[partner];
            bool before = (va > vb) || (va == vb && ia < ib);
            bool asc = ((l & k) == 0);
            bool doSwap = asc ? (!before) : before;
            if (doSwap) { v[l] = vb; v[partner] = va; ix[l] = ib; ix[partner] = ia; }
            __syncthreads();
        }
    }
    lams[t] = v[t]; lams[t + 1024] = v[t + 1024];
    order[t] = ix[t]; order[t + 1024] = ix[t + 1024];
}

__global__ void k_out(const float* __restrict__ Vm, const double* __restrict__ lams,
                      const int* __restrict__ order, float* __restrict__ out) {
    int c = blockIdx.x, t = threadIdx.x;
    int col = order[c];
    __shared__ float rv[256]; __shared__ int ri[256];
    float bv = -1.f; int bidx = N;
    for (int i = t; i < N; i += 256) {
        float av = fabsf(Vm[(size_t)i * N + col]);
        if (av > bv || (av == bv && i < bidx)) { bv = av; bidx = i; }
    }
    rv[t] = bv; ri[t] = bidx;
    __syncthreads();
    for (int off = 128; off; off >>= 1) {
        if (t < off) {
            if (rv[t + off] > rv[t] || (rv[t + off] == rv[t] && ri[t + off] < ri[t])) {
                rv[t] = rv[t + off]; ri[t] = ri[t + off];
            }
        }
        __syncthreads();
    }
    float sv = Vm[(size_t)ri[0] * N + col];
    float s = (sv > 0.f) ? 1.f : ((sv < 0.f) ? -1.f : 0.f);
    double lv = lams[c];
    float f = s * (float)sqrt(lv > 0.0 ? lv : 0.0);
    for (int i = t; i < N; i += 256) out[(size_t)i * NC + c] = Vm[(size_t)i * N + col] * f;
}

extern "C" void kernel_launch(void* const* d_in, const int* in_sizes, int n_in,
                              void* d_out, int out_size, void* d_ws, size_t ws_size,
                              hipStream_t stream) {
    (void)in_sizes; (void)n_in; (void)out_size; (void)ws_size;
    const float* X = (const float*)d_in[0];
    float* out = (float*)d_out;

    double* rm  = (double*)d_ws;                 // N
    double* gm  = rm + N;                        // 1 (+7 pad)
    double* lam = gm + 8;                        // N
    double* lams= lam + N;                       // N
    double* A   = lams + N;                      // N*N fp64
    double* qb  = A + (size_t)N * N;             // 2 * NPAIRS*1024 fp64 (double-buffered)
    float* Dg   = (float*)(qb + 2 * (size_t)NPAIRS * 1024); // N*N f32
    float* Vm   = Dg + (size_t)N * N;            // N*N f32
    float* sq   = Vm + (size_t)N * N;            // N
    int* order  = (int*)(sq + N);                // N
    int* qfl    = order + N;                     // 2 * NPAIRS
    unsigned* flags = (unsigned*)(qfl + 2 * NPAIRS); // 3
    float* dist = (float*)A;                     // alias: dist dies before A is born

    // 1. pairwise distances
    k_rowsq<<<N / 4, 256, 0, stream>>>(X, sq);
    k_dist<<<dim3(32, 32), 256, 0, stream>>>(X, sq, dist);

    // 2. KNN graph
    k_knn<<<N, 256, 0, stream>>>(dist, Dg);
    k_symdiag<<<(N * N) / 256, 256, 0, stream>>>(Dg);

    // 3. blocked Floyd-Warshall
    for (int kb = 0; kb < N / 64; kb++) {
        k_fw12<<<63, 256, 0, stream>>>(Dg, kb);
        k_fw3<<<dim3(32, 32), 256, 0, stream>>>(Dg, kb);
    }

    // 4. double centering -> B (fp64)
    k_rowmean<<<N, 256, 0, stream>>>(Dg, rm);
    k_grand<<<1, 256, 0, stream>>>(rm, gm);
    k_buildB<<<(N * N) / 256, 256, 0, stream>>>(Dg, rm, gm, A);
    k_setV<<<(N * N) / 256, 256, 0, stream>>>(Vm);
    k_initflags<<<1, 1, 0, stream>>>(flags);

    // 5. pipelined two-sided block Jacobi, ONE launch per round, compact grid:
    //    local(0) prologue; per round g: fused{ critTri(g)+local(g+1) || tri_rest(g)x2 || V(g)x2 }.
    const int G = NSWEEPS * (NB - 1);
    k_local0<<<NPAIRS, 256, 0, stream>>>(A, qb, qfl, flags);
    for (int g = 0; g < G; g++) {
        int round = g % (NB - 1), par = g & 1;
        int nr = (g + 1) % (NB - 1), npar = (g + 1) & 1;
        int nv = (g + 1 < G) ? 1 : 0;
        if (((g + 1) % (NB - 1)) == 0)
            k_sweepctl<<<1, 1, 0, stream>>>(flags);
        k_fused<<<NPAIRS + NTRIB + NVB, 256, 0, stream>>>(A, Vm, qb, qfl, flags,
                                                          round, par, nr, npar, nv);
    }

    // 6. sort eigenvalues, sign-fix, scale, write output
    k_lambda<<<N / 256, 256, 0, stream>>>(A, lam);
    k_sort<<<1, 1024, 0, stream>>>(lam, lams, order);
    k_out<<<NC, 256, 0, stream>>>(Vm, lams, order, out);
}

// Round 11
// 58758.948 us; speedup vs baseline: 2.2560x; 1.0441x over previous
//
#include <hip/hip_runtime.h>
#include <math.h>

#define N 2048
#define DIMS 784
#define BIGV 1.0e6f
#define NC 784

// two-sided block Jacobi config: 128 teams of width 16, 32x32 local tiles
#define NB 128
#define NPAIRS 64
#define NSWEEPS 18
#define NTRI 2016      // 64*63/2 upper-tri pair tiles
#define NVS  2048      // 64 pairs * 32 V row-stripes
#define GRID 2048      // exact co-residency fit: 8 blocks/CU x 256 CU

typedef __attribute__((ext_vector_type(4))) double d4_t;

// round-robin pairing over nteams: round r in [0,nteams-1), pair m in [0,nteams/2)
__device__ __forceinline__ void rr_pairN(int r, int m, int nteams, int& bi, int& bj) {
    int n1 = nteams - 1;
    if (m == 0) { bi = n1; bj = r % n1; }
    else { bi = (r + m) % n1; bj = (r - m + n1) % n1; }
}

// pair index of team x in round r (NB teams)
__device__ __forceinline__ int rr_pidx(int r, int x) {
    const int n1 = NB - 1;
    if (x == n1) return 0;
    int m = (x - r) % n1; if (m < 0) m += n1;
    if (m == 0) return 0;
    return (m <= n1 / 2) ? m : n1 - m;
}
// partner team of x in round r
__device__ __forceinline__ int rr_partner(int r, int x) {
    const int n1 = NB - 1;
    if (x == n1) return r % n1;
    int m = (x - r) % n1; if (m < 0) m += n1;
    if (m == 0) return n1;
    if (m <= n1 / 2) return (r - m + n1) % n1;
    int m2 = n1 - m; return (r + m2) % n1;
}

// A is stored CANONICALLY: 16x16 team-sub-block (u,v) valid only at u<=v.

// ---------------- distances ----------------
__global__ void k_rowsq(const float* __restrict__ X, float* __restrict__ sq) {
    int wave = threadIdx.x >> 6, lane = threadIdx.x & 63;
    int row = blockIdx.x * 4 + wave;
    const float* xr = X + (size_t)row * DIMS;
    float s = 0.f;
    for (int k = lane; k < DIMS; k += 64) { float v = xr[k]; s += v * v; }
    for (int off = 32; off; off >>= 1) s += __shfl_down(s, off);
    if (lane == 0) sq[row] = s;
}

__global__ void __launch_bounds__(256) k_dist(const float* __restrict__ X,
                                              const float* __restrict__ sq,
                                              float* __restrict__ out) {
    __shared__ float As[64][17], Bs[64][17];
    int ti = blockIdx.y, tj = blockIdx.x, t = threadIdx.x;
    int tx = t & 15, ty = t >> 4;
    float acc[4][4] = {};
    for (int k0 = 0; k0 < DIMS; k0 += 16) {
        for (int e = 0; e < 4; e++) {
            int idx = t + e * 256; int r = idx >> 4, c = idx & 15;
            As[r][c] = X[(size_t)(ti * 64 + r) * DIMS + k0 + c];
            Bs[r][c] = X[(size_t)(tj * 64 + r) * DIMS + k0 + c];
        }
        __syncthreads();
        for (int k = 0; k < 16; k++) {
            float a[4], b[4];
            for (int e = 0; e < 4; e++) a[e] = As[ty * 4 + e][k];
            for (int f = 0; f < 4; f++) b[f] = Bs[tx * 4 + f][k];
            for (int e = 0; e < 4; e++)
                for (int f = 0; f < 4; f++) acc[e][f] += a[e] * b[f];
        }
        __syncthreads();
    }
    for (int e = 0; e < 4; e++)
        for (int f = 0; f < 4; f++) {
            int gi = ti * 64 + ty * 4 + e, gj = tj * 64 + tx * 4 + f;
            float d2 = sq[gi] + sq[gj] - 2.f * acc[e][f];
            out[(size_t)gi * N + gj] = sqrtf(fmaxf(d2, 0.f));
        }
}

// ---------------- KNN graph ----------------
__global__ void k_knn(const float* __restrict__ dist, float* __restrict__ G) {
    int i = blockIdx.x, t = threadIdx.x;
    float bv[6]; int bidx[6];
    for (int k = 0; k < 6; k++) { bv[k] = 3.4e38f; bidx[k] = N; }
    const float* dr = dist + (size_t)i * N;
    for (int j = t; j < N; j += 256) {
        float v = dr[j];
        bool ins = (v < bv[5]) || (v == bv[5] && j < bidx[5]);
        if (ins) {
            int k = 5;
            while (k > 0) {
                bool mv = (v < bv[k - 1]) || (v == bv[k - 1] && j < bidx[k - 1]);
                if (!mv) break;
                bv[k] = bv[k - 1]; bidx[k] = bidx[k - 1]; k--;
            }
            bv[k] = v; bidx[k] = j;
        }
    }
    __shared__ float lv[256][6]; __shared__ int li[256][6];
    for (int k = 0; k < 6; k++) { lv[t][k] = bv[k]; li[t][k] = bidx[k]; }
    __syncthreads();
    for (int off = 128; off >= 1; off >>= 1) {
        if (t < off) {
            float av[6], cv[6]; int ai[6], ci[6];
            for (int k = 0; k < 6; k++) { av[k] = lv[t][k]; ai[k] = li[t][k]; cv[k] = lv[t + off][k]; ci[k] = li[t + off][k]; }
            float mv[6]; int mi[6]; int pa = 0, pb = 0;
            for (int k = 0; k < 6; k++) {
                bool ta;
                if (pa >= 6) ta = false;
                else if (pb >= 6) ta = true;
                else ta = (av[pa] < cv[pb]) || (av[pa] == cv[pb] && ai[pa] < ci[pb]);
                if (ta) { mv[k] = av[pa]; mi[k] = ai[pa]; pa++; }
                else    { mv[k] = cv[pb]; mi[k] = ci[pb]; pb++; }
            }
            for (int k = 0; k < 6; k++) { lv[t][k] = mv[k]; li[t][k] = mi[k]; }
        }
        __syncthreads();
    }
    float sv[6]; int si[6];
    for (int k = 0; k < 6; k++) { sv[k] = lv[0][k]; si[k] = li[0][k]; }
    for (int j = t; j < N; j += 256) {
        float val = BIGV;
        for (int k = 0; k < 6; k++) if (j == si[k]) val = sv[k];
        G[(size_t)i * N + j] = val;
    }
}

__global__ void k_symdiag(float* __restrict__ G) {
    int idx = blockIdx.x * 256 + threadIdx.x;
    int i = idx >> 11, j = idx & 2047;
    if (i == j) { G[idx] = 0.f; return; }
    if (j > i) {
        float a = G[(size_t)i * N + j], b = G[(size_t)j * N + i];
        float m = fminf(a, b);
        G[(size_t)i * N + j] = m; G[(size_t)j * N + i] = m;
    }
}

// ---------------- blocked Floyd-Warshall ----------------
__global__ void __launch_bounds__(256) k_fw12(float* __restrict__ D, int kb) {
    __shared__ float KK[64][65], C[64][65];
    int bx = blockIdx.x, t = threadIdx.x;
    for (int e = 0; e < 16; e++) { int idx = t + e * 256; int r = idx >> 6, c = idx & 63;
        KK[r][c] = D[(size_t)(kb * 64 + r) * N + kb * 64 + c]; }
    __syncthreads();
    int r0 = t >> 2, c0 = (t & 3) * 16;
    for (int k = 0; k < 64; k++) {
        float dk = KK[r0][k];
        for (int c = 0; c < 16; c++) KK[r0][c0 + c] = fminf(KK[r0][c0 + c], dk + KK[k][c0 + c]);
        __syncthreads();
    }
    if (bx == 62) {
        for (int e = 0; e < 16; e++) { int idx = t + e * 256; int r = idx >> 6, c = idx & 63;
            D[(size_t)(kb * 64 + r) * N + kb * 64 + c] = KK[r][c]; }
        return;
    }
    bool rowstripe = bx < 31;
    int o = rowstripe ? bx : bx - 31;
    o += (o >= kb) ? 1 : 0;
    int baseR = rowstripe ? kb : o;
    int baseC = rowstripe ? o : kb;
    for (int e = 0; e < 16; e++) { int idx = t + e * 256; int r = idx >> 6, c = idx & 63;
        C[r][c] = D[(size_t)(baseR * 64 + r) * N + baseC * 64 + c]; }
    __syncthreads();
    if (rowstripe) {
        for (int k = 0; k < 64; k++) {
            float dk = KK[r0][k];
            for (int c = 0; c < 16; c++) C[r0][c0 + c] = fminf(C[r0][c0 + c], dk + C[k][c0 + c]);
            __syncthreads();
        }
    } else {
        for (int k = 0; k < 64; k++) {
            float dk = C[r0][k];
            for (int c = 0; c < 16; c++) C[r0][c0 + c] = fminf(C[r0][c0 + c], dk + KK[k][c0 + c]);
            __syncthreads();
        }
    }
    for (int e = 0; e < 16; e++) { int idx = t + e * 256; int r = idx >> 6, c = idx & 63;
        D[(size_t)(baseR * 64 + r) * N + baseC * 64 + c] = C[r][c]; }
}

__global__ void __launch_bounds__(256) k_fw3(float* __restrict__ D, int kb) {
    int bi = blockIdx.y, bj = blockIdx.x;
    if (bi == kb || bj == kb) return;
    __shared__ float R[64][65], Cl[64][65];
    int t = threadIdx.x;
    for (int e = 0; e < 16; e++) { int idx = t + e * 256; int r = idx >> 6, c = idx & 63;
        R[r][c]  = D[(size_t)(bi * 64 + r) * N + kb * 64 + c];
        Cl[r][c] = D[(size_t)(kb * 64 + r) * N + bj * 64 + c]; }
    __syncthreads();
    int r0 = (t >> 4) * 4, c0 = (t & 15) * 4;
    float acc[4][4];
    for (int e = 0; e < 4; e++) for (int f = 0; f < 4; f++) acc[e][f] = 3.4e38f;
    for (int k = 0; k < 64; k++) {
        float a[4], b[4];
        for (int e = 0; e < 4; e++) a[e] = R[r0 + e][k];
        for (int f = 0; f < 4; f++) b[f] = Cl[k][c0 + f];
        for (int e = 0; e < 4; e++)
            for (int f = 0; f < 4; f++) acc[e][f] = fminf(acc[e][f], a[e] + b[f]);
    }
    for (int e = 0; e < 4; e++)
        for (int f = 0; f < 4; f++) {
            size_t off = (size_t)(bi * 64 + r0 + e) * N + bj * 64 + c0 + f;
            D[off] = fminf(D[off], acc[e][f]);
        }
}

// ---------------- double centering ----------------
__global__ void k_rowmean(const float* __restrict__ D, double* __restrict__ rm) {
    int i = blockIdx.x, t = threadIdx.x;
    const float* dr = D + (size_t)i * N;
    double s = 0;
    for (int j = t; j < N; j += 256) { double d = (double)dr[j]; s += d * d; }
    __shared__ double red[256];
    red[t] = s; __syncthreads();
    for (int off = 128; off; off >>= 1) { if (t < off) red[t] += red[t + off]; __syncthreads(); }
    if (t == 0) rm[i] = red[0] / (double)N;
}

__global__ void k_grand(const double* __restrict__ rm, double* __restrict__ gm) {
    int t = threadIdx.x;
    double s = 0;
    for (int i = t; i < N; i += 256) s += rm[i];
    __shared__ double red[256];
    red[t] = s; __syncthreads();
    for (int off = 128; off; off >>= 1) { if (t < off) red[t] += red[t + off]; __syncthreads(); }
    if (t == 0) gm[0] = red[0] / (double)N;
}

__global__ void k_buildB(const float* __restrict__ D, const double* __restrict__ rm,
                         const double* __restrict__ gm, double* __restrict__ A) {
    int idx = blockIdx.x * 256 + threadIdx.x;
    int i = idx >> 11, j = idx & 2047;
    double d = (double)D[idx];
    A[idx] = -0.5 * (d * d - rm[i] - rm[j] + gm[0]);
}

__global__ void k_setV(float* __restrict__ V) {
    int idx = blockIdx.x * 256 + threadIdx.x;
    int i = idx >> 11, j = idx & 2047;
    V[idx] = (i == j) ? 1.f : 0.f;
}

// ---------------- Jacobi control ----------------
__global__ void k_initflags(unsigned* flags) { flags[0] = 0u; flags[1] = 0u; flags[2] = 0u; }
__global__ void k_sweepctl(unsigned* flags) {
    if (!flags[2]) {
        float mo = __uint_as_float(flags[0]), md = __uint_as_float(flags[1]);
        if (md > 0.f && mo <= 2e-9f * md) { flags[2] = 1u; return; }
        flags[0] = 0u; flags[1] = 0u;
    }
}

// ---------------- task bodies (shared-union via smem base pointer) ----------------
// smem: double[2432] = 19456 B per block.

// V <- V*Q for one 64-row stripe
__device__ __forceinline__ void vapply_task(float* __restrict__ V, const double* __restrict__ qbP,
                                            const int* __restrict__ qp, int rnd, int task, int t,
                                            double* smem) {
    int p = task >> 5, rt = task & 31;
    if (!qp[p]) return;
    float (*Qs)[33] = (float(*)[33])smem;
    float (*Tv)[33] = (float(*)[33])(smem + 528);
    int bi, bj; rr_pairN(rnd, p, NB, bi, bj);
    for (int e = 0; e < 4; e++) {
        int idx = t + e * 256; int a = idx >> 5, c = idx & 31;
        Qs[a][c] = (float)qbP[(size_t)p * 1024 + idx];
    }
    for (int e = 0; e < 8; e++) {
        int idx = t + e * 256; int a = idx >> 5, c = idx & 31;
        int gc = (c < 16) ? bi * 16 + c : bj * 16 + (c - 16);
        Tv[a][c] = V[(size_t)(rt * 64 + a) * N + gc];
    }
    __syncthreads();
    int r0 = (t >> 4) * 4, c0 = (t & 15) * 2;
    float acc[4][2] = {};
    for (int y = 0; y < 32; y++) {
        float q0 = Qs[y][c0], q1 = Qs[y][c0 + 1];
        for (int e = 0; e < 4; e++) {
            float vv = Tv[r0 + e][y];
            acc[e][0] += vv * q0; acc[e][1] += vv * q1;
        }
    }
    for (int e = 0; e < 4; e++)
        for (int f = 0; f < 2; f++) {
            int x = c0 + f;
            int gc = (x < 16) ? bi * 16 + x : bj * 16 + (x - 16);
            V[(size_t)(rt * 64 + r0 + e) * N + gc] = acc[e][f];
        }
}

// local 32x32 Jacobi on pair p of `round` (4 waves, fused two-sided update,
// 2 barriers per micro-round: thread (m1,m2) applies J^T(m1)·[2x2]·J(m2) in regs).
__device__ __forceinline__ void local_task(double* __restrict__ A, double* __restrict__ qb,
                                           int* __restrict__ qfl, unsigned* __restrict__ flags,
                                           int round, int par, int p, int t, double* smem) {
    double* qbC = qb + (size_t)par * (NPAIRS * 1024);
    int* qflC = qfl + par * NPAIRS;
    if (flags[2]) { if (t == 0) qflC[p] = 0; return; }
    double (*M)[33] = (double(*)[33])smem;
    double (*Q)[33] = (double(*)[33])(smem + 1056);
    double* cA = smem + 2112; double* sA = smem + 2128;
    int* ppA = (int*)(smem + 2144); int* qqA = ppA + 16;
    float* rbuf = (float*)(smem + 2160);       // 8 floats: per-wave off/diag maxima
    int* everr = (int*)(smem + 2416);
    int bi, bj; rr_pairN(round, p, NB, bi, bj);

    int rr = t >> 4, cc = t & 15;
    int tm[2] = { bi, bj };
    float offm = 0.f, diagm = 0.f;
    for (int s = 0; s < 4; s++) {
        int u = tm[s >> 1], v = tm[s & 1];
        double val; int dr, dc;
        if (u <= v) { val = A[(size_t)(u * 16 + rr) * N + v * 16 + cc]; dr = (s >> 1) * 16 + rr; dc = (s & 1) * 16 + cc; }
        else        { val = A[(size_t)(v * 16 + rr) * N + u * 16 + cc]; dr = (s >> 1) * 16 + cc; dc = (s & 1) * 16 + rr; }
        M[dr][dc] = val;
        float av = (float)fabs(val);
        if (s == 0 || s == 3) { if (rr == cc) diagm = fmaxf(diagm, av); else offm = fmaxf(offm, av); }
        else offm = fmaxf(offm, av);
    }
    for (int e = 0; e < 4; e++) {
        int idx = t + e * 256; int x = idx >> 5, y = idx & 31;
        Q[x][y] = (x == y) ? 1.0 : 0.0;
    }
    // per-wave shuffle max, then one barrier
    for (int off = 32; off; off >>= 1) {
        offm = fmaxf(offm, __shfl_down(offm, off));
        diagm = fmaxf(diagm, __shfl_down(diagm, off));
    }
    if ((t & 63) == 0) { rbuf[t >> 6] = offm; rbuf[4 + (t >> 6)] = diagm; }
    if (t == 0) *everr = 0;
    __syncthreads();
    float off0 = fmaxf(fmaxf(rbuf[0], rbuf[1]), fmaxf(rbuf[2], rbuf[3]));
    float dmaxf = fmaxf(fmaxf(rbuf[4], rbuf[5]), fmaxf(rbuf[6], rbuf[7]));
    if (t == 0) { atomicMax(flags + 0, __float_as_uint(off0)); atomicMax(flags + 1, __float_as_uint(dmaxf)); }
    double dmax = (double)dmaxf;
    if ((double)off0 <= 1e-9 * dmax) { if (t == 0) qflC[p] = 0; return; }
    double thr = fmax(1e-13 * dmax, 1e-5 * (double)off0);

    int m1 = t >> 4, m2 = t & 15;
    for (int ir = 0; ir < 31; ir++) {
        if (t < 16) {
            int pp, qq; rr_pairN(ir, t, 32, pp, qq);
            double app = M[pp][pp], aqq = M[qq][qq], apq = M[pp][qq];
            double c = 1.0, sn = 0.0;
            if (fabs(apq) > thr) {
                double tau = (aqq - app) / (2.0 * apq);
                double tt2 = ((tau >= 0.0) ? 1.0 : -1.0) / (fabs(tau) + sqrt(1.0 + tau * tau));
                c = 1.0 / sqrt(1.0 + tt2 * tt2);
                sn = tt2 * c;
                *everr = 1;
            }
            ppA[t] = pp; qqA[t] = qq; cA[t] = c; sA[t] = sn;
        }
        __syncthreads();
        // fused two-sided M update: thread (m1,m2) owns the 2x2 block
        {
            double s1 = sA[m1], s2 = sA[m2];
            if (s1 != 0.0 || s2 != 0.0) {
                int p1 = ppA[m1], q1 = qqA[m1];
                int p2 = ppA[m2], q2 = qqA[m2];
                double c1 = cA[m1], c2 = cA[m2];
                double a = M[p1][p2], b = M[p1][q2];
                double cx = M[q1][p2], d = M[q1][q2];
                double a1 = c2 * a - s2 * b,  b1 = s2 * a + c2 * b;
                double c1v = c2 * cx - s2 * d, d1 = s2 * cx + c2 * d;
                M[p1][p2] = c1 * a1 - s1 * c1v; M[p1][q2] = c1 * b1 - s1 * d1;
                M[q1][p2] = s1 * a1 + c1 * c1v; M[q1][q2] = s1 * b1 + c1 * d1;
            }
            // Q col update: Q <- Q*J (512 slots, 2/thread)
            for (int e = 0; e < 2; e++) {
                int slot = t + e * 256; int mm = slot >> 5, k = slot & 31;
                double snq = sA[mm];
                if (snq != 0.0) {
                    int pp = ppA[mm], qq = qqA[mm]; double cq = cA[mm];
                    double qa = Q[k][pp], qb = Q[k][qq];
                    Q[k][pp] = cq * qa - snq * qb; Q[k][qq] = snq * qa + cq * qb;
                }
            }
        }
        __syncthreads();
    }
    int ev = *everr;
    if (t == 0) qflC[p] = ev;
    if (ev) {
        for (int e = 0; e < 4; e++) {
            int idx = t + e * 256; int x = idx >> 5, y = idx & 31;
            qbC[(size_t)p * 1024 + idx] = Q[x][y];
        }
        A[(size_t)(bi * 16 + rr) * N + bi * 16 + cc] = M[rr][cc];
        A[(size_t)(bj * 16 + rr) * N + bj * 16 + cc] = M[16 + rr][16 + cc];
        if (bi <= bj) A[(size_t)(bi * 16 + rr) * N + bj * 16 + cc] = M[rr][16 + cc];
        else          A[(size_t)(bj * 16 + rr) * N + bi * 16 + cc] = M[16 + rr][cc];
    }
}

// tri-apply: A <- Qr^T A Qc on pair tile (pr,pc), fp64 MFMA, canonical storage
__device__ __forceinline__ void tri_task(double* __restrict__ A, const double* __restrict__ qbC,
                                         const int* __restrict__ qflC, int round, int pr, int pc,
                                         int t, double* smem) {
    int fr = qflC[pr], fc = qflC[pc];
    if (!fr && !fc) return;
    double (*T)[33] = (double(*)[33])smem;
    double (*Qb)[33] = (double(*)[33])(smem + 1056);
    int bir, bjr, bic, bjc;
    rr_pairN(round, pr, NB, bir, bjr);
    rr_pairN(round, pc, NB, bic, bjc);
    int rt[2] = { bir, bjr }, ct[2] = { bic, bjc };
    int rr = t >> 4, cc = t & 15;
    if (fr) {
        for (int e = 0; e < 4; e++) {
            int idx = t + e * 256; int a = idx >> 5, b = idx & 31;
            Qb[a][b] = qbC[(size_t)pr * 1024 + idx];
        }
    }
    for (int s = 0; s < 4; s++) {
        int u = rt[s >> 1], v = ct[s & 1];
        if (u <= v) T[(s >> 1) * 16 + rr][(s & 1) * 16 + cc] = A[(size_t)(u * 16 + rr) * N + v * 16 + cc];
        else        T[(s >> 1) * 16 + cc][(s & 1) * 16 + rr] = A[(size_t)(v * 16 + rr) * N + u * 16 + cc];
    }
    __syncthreads();
    int wv = t >> 6, ln = t & 63;
    int i0 = (wv >> 1) * 16, j0 = (wv & 1) * 16;
    int li = ln & 15, lk = ln >> 4;
    if (fr) {
        d4_t d = {0.0, 0.0, 0.0, 0.0};
        #pragma unroll
        for (int y0 = 0; y0 < 32; y0 += 4) {
            double a = Qb[y0 + lk][i0 + li];
            double b = T[y0 + lk][j0 + li];
            d = __builtin_amdgcn_mfma_f64_16x16x4f64(a, b, d, 0, 0, 0);
        }
        __syncthreads();
        #pragma unroll
        for (int v = 0; v < 4; v++) T[i0 + lk * 4 + v][j0 + li] = d[v];
        __syncthreads();
    }
    if (fc) {
        for (int e = 0; e < 4; e++) {
            int idx = t + e * 256; int a = idx >> 5, b = idx & 31;
            Qb[a][b] = qbC[(size_t)pc * 1024 + idx];
        }
        __syncthreads();
        d4_t d = {0.0, 0.0, 0.0, 0.0};
        #pragma unroll
        for (int y0 = 0; y0 < 32; y0 += 4) {
            double a = T[i0 + li][y0 + lk];
            double b = Qb[y0 + lk][j0 + li];
            d = __builtin_amdgcn_mfma_f64_16x16x4f64(a, b, d, 0, 0, 0);
        }
        __syncthreads();
        #pragma unroll
        for (int v = 0; v < 4; v++) T[i0 + lk * 4 + v][j0 + li] = d[v];
        __syncthreads();
    }
    for (int s = 0; s < 4; s++) {
        int u = rt[s >> 1], v = ct[s & 1];
        if (u <= v) A[(size_t)(u * 16 + rr) * N + v * 16 + cc] = T[(s >> 1) * 16 + rr][(s & 1) * 16 + cc];
        else        A[(size_t)(v * 16 + rr) * N + u * 16 + cc] = T[(s >> 1) * 16 + cc][(s & 1) * 16 + rr];
    }
}

// ---------------- pipelined Jacobi kernels ----------------
// round 0 local, standalone prologue
__global__ void __launch_bounds__(256) k_local0(double* __restrict__ A, double* __restrict__ qb,
                                                int* __restrict__ qfl, unsigned* __restrict__ flags) {
    __shared__ double smem[2432];
    local_task(A, qb, qfl, flags, 0, 0, (int)blockIdx.x, (int)threadIdx.x, smem);
}

// fused single launch per round (exact 2048-block grid, one co-residency wave):
//   blocks 0..63: setprio(1) { critical tri(round) ; local(nextRound) } setprio(0)
//   blocks 64..2047: unified balanced list of {tri_rest(round), V(round)} tasks
__global__ void __launch_bounds__(256) k_fused(double* __restrict__ A, float* __restrict__ V,
                                               double* __restrict__ qb, int* __restrict__ qfl,
                                               unsigned* __restrict__ flags,
                                               int round, int par, int nextRound, int nextPar,
                                               int nextValid) {
    __shared__ double smem[2432];
    int t = threadIdx.x, blk = blockIdx.x;
    if (blk < NPAIRS) {
        __builtin_amdgcn_s_setprio(1);     // critical-path blocks: favor on CU scheduler
        if (!flags[2]) {
            int u, v; rr_pairN(nextRound, blk, NB, u, v);
            int a = rr_pidx(round, u), b = rr_pidx(round, v);
            int pr = min(a, b), pc = max(a, b);
            tri_task(A, qb + (size_t)par * (NPAIRS * 1024), qfl + par * NPAIRS,
                     round, pr, pc, t, smem);
            __syncthreads();
        }
        if (nextValid) local_task(A, qb, qfl, flags, nextRound, nextPar, blk, t, smem);
        __builtin_amdgcn_s_setprio(0);
    } else {
        if (flags[2]) return;
        // unified task list: [0, NTRI) = tri_rest (crit skipped), [NTRI, NTRI+NVS) = V stripes
        for (int idx = blk - NPAIRS; idx < NTRI + NVS; idx += GRID - NPAIRS) {
            if (idx < NTRI) {
                int pr = 0, rem = idx;
                while (rem >= 63 - pr) { rem -= 63 - pr; pr++; }
                int pc = pr + 1 + rem;
                int bir, bjr, bic, bjc;
                rr_pairN(round, pr, NB, bir, bjr);
                rr_pairN(round, pc, NB, bic, bjc);
                bool crit = false;
                #pragma unroll
                for (int s = 0; s < 4; s++) {
                    int tu = (s >> 1) ? bjr : bir, tv = (s & 1) ? bjc : bic;
                    if (rr_partner(nextRound, tu) == tv) crit = true;  // handled by local blocks
                }
                if (!crit)
                    tri_task(A, qb + (size_t)par * (NPAIRS * 1024), qfl + par * NPAIRS,
                             round, pr, pc, t, smem);
            } else {
                vapply_task(V, qb + (size_t)par * (NPAIRS * 1024), qfl + par * NPAIRS,
                            round, idx - NTRI, t, smem);
            }
            __syncthreads();   // protect smem reuse between successive tasks
        }
    }
}

// ---------------- epilogue ----------------
__global__ void k_lambda(const double* __restrict__ A, double* __restrict__ lam) {
    int i = blockIdx.x * 256 + threadIdx.x;
    if (i < N) lam[i] = A[(size_t)i * N + i];
}

__global__ void __launch_bounds__(1024) k_sort(const double* __restrict__ lam,
                                               double* __restrict__ lams, int* __restrict__ order) {
    __shared__ double v[2048]; __shared__ int ix[2048];
    int t = threadIdx.x;
    v[t] = lam[t]; v[t + 1024] = lam[t + 1024];
    ix[t] = t; ix[t + 1024] = t + 1024;
    __syncthreads();
    for (int k = 2; k <= 2048; k <<= 1) {
        for (int j = k >> 1; j > 0; j >>= 1) {
            int l = ((t & ~(j - 1)) << 1) | (t & (j - 1));
            int partner = l | j;
            double va = v[l], vb = v[partner]; int ia = ix[l], ib = ix[partner];
            bool before = (va > vb) || (va == vb && ia < ib);
            bool asc = ((l & k) == 0);
            bool doSwap = asc ? (!before) : before;
            if (doSwap) { v[l] = vb; v[partner] = va; ix[l] = ib; ix[partner] = ia; }
            __syncthreads();
        }
    }
    lams[t] = v[t]; lams[t + 1024] = v[t + 1024];
    order[t] = ix[t]; order[t + 1024] = ix[t + 1024];
}

__global__ void k_out(const float* __restrict__ Vm, const double* __restrict__ lams,
                      const int* __restrict__ order, float* __restrict__ out) {
    int c = blockIdx.x, t = threadIdx.x;
    int col = order[c];
    __shared__ float rv[256]; __shared__ int ri[256];
    float bv = -1.f; int bidx = N;
    for (int i = t; i < N; i += 256) {
        float av = fabsf(Vm[(size_t)i * N + col]);
        if (av > bv || (av == bv && i < bidx)) { bv = av; bidx = i; }
    }
    rv[t] = bv; ri[t] = bidx;
    __syncthreads();
    for (int off = 128; off; off >>= 1) {
        if (t < off) {
            if (rv[t + off] > rv[t] || (rv[t + off] == rv[t] && ri[t + off] < ri[t])) {
                rv[t] = rv[t + off]; ri[t] = ri[t + off];
            }
        }
        __syncthreads();
    }
    float sv = Vm[(size_t)ri[0] * N + col];
    float s = (sv > 0.f) ? 1.f : ((sv < 0.f) ? -1.f : 0.f);
    double lv = lams[c];
    float f = s * (float)sqrt(lv > 0.0 ? lv : 0.0);
    for (int i = t; i < N; i += 256) out[(size_t)i * NC + c] = Vm[(size_t)i * N + col] * f;
}

extern "C" void kernel_launch(void* const* d_in, const int* in_sizes, int n_in,
                              void* d_out, int out_size, void* d_ws, size_t ws_size,
                              hipStream_t stream) {
    (void)in_sizes; (void)n_in; (void)out_size; (void)ws_size;
    const float* X = (const float*)d_in[0];
    float* out = (float*)d_out;

    double* rm  = (double*)d_ws;                 // N
    double* gm  = rm + N;                        // 1 (+7 pad)
    double* lam = gm + 8;                        // N
    double* lams= lam + N;                       // N
    double* A   = lams + N;                      // N*N fp64
    double* qb  = A + (size_t)N * N;             // 2 * NPAIRS*1024 fp64 (double-buffered)
    float* Dg   = (float*)(qb + 2 * (size_t)NPAIRS * 1024); // N*N f32
    float* Vm   = Dg + (size_t)N * N;            // N*N f32
    float* sq   = Vm + (size_t)N * N;            // N
    int* order  = (int*)(sq + N);                // N
    int* qfl    = order + N;                     // 2 * NPAIRS
    unsigned* flags = (unsigned*)(qfl + 2 * NPAIRS); // 3
    float* dist = (float*)A;                     // alias: dist dies before A is born

    // 1. pairwise distances
    k_rowsq<<<N / 4, 256, 0, stream>>>(X, sq);
    k_dist<<<dim3(32, 32), 256, 0, stream>>>(X, sq, dist);

    // 2. KNN graph
    k_knn<<<N, 256, 0, stream>>>(dist, Dg);
    k_symdiag<<<(N * N) / 256, 256, 0, stream>>>(Dg);

    // 3. blocked Floyd-Warshall
    for (int kb = 0; kb < N / 64; kb++) {
        k_fw12<<<63, 256, 0, stream>>>(Dg, kb);
        k_fw3<<<dim3(32, 32), 256, 0, stream>>>(Dg, kb);
    }

    // 4. double centering -> B (fp64)
    k_rowmean<<<N, 256, 0, stream>>>(Dg, rm);
    k_grand<<<1, 256, 0, stream>>>(rm, gm);
    k_buildB<<<(N * N) / 256, 256, 0, stream>>>(Dg, rm, gm, A);
    k_setV<<<(N * N) / 256, 256, 0, stream>>>(Vm);
    k_initflags<<<1, 1, 0, stream>>>(flags);

    // 5. pipelined two-sided block Jacobi, ONE launch per round, exact-fit grid:
    //    local(0) prologue; per round g: fused{ critTri(g)+local(g+1) || tri_rest(g)/V(g) balanced }.
    const int G = NSWEEPS * (NB - 1);
    k_local0<<<NPAIRS, 256, 0, stream>>>(A, qb, qfl, flags);
    for (int g = 0; g < G; g++) {
        int round = g % (NB - 1), par = g & 1;
        int nr = (g + 1) % (NB - 1), npar = (g + 1) & 1;
        int nv = (g + 1 < G) ? 1 : 0;
        if (((g + 1) % (NB - 1)) == 0)
            k_sweepctl<<<1, 1, 0, stream>>>(flags);
        k_fused<<<GRID, 256, 0, stream>>>(A, Vm, qb, qfl, flags,
                                          round, par, nr, npar, nv);
    }

    // 6. sort eigenvalues, sign-fix, scale, write output
    k_lambda<<<N / 256, 256, 0, stream>>>(A, lam);
    k_sort<<<1, 1024, 0, stream>>>(lam, lams, order);
    k_out<<<NC, 256, 0, stream>>>(Vm, lams, order, out);
}